// Round 1
// baseline (315.307 us; speedup 1.0000x reference)
//
#include <hip/hip_runtime.h>

typedef unsigned short u16;
typedef __attribute__((ext_vector_type(8))) __bf16 bf16x8;
typedef __attribute__((ext_vector_type(8))) u16 u16x8;
typedef __attribute__((ext_vector_type(4))) float f32x4;
typedef __attribute__((ext_vector_type(16))) float f32x16;

__device__ __forceinline__ float bf2f(u16 u){
  union { unsigned int i; float f; } v; v.i = ((unsigned int)u) << 16; return v.f;
}
__device__ __forceinline__ u16 f2bf(float f){
  union { float f; unsigned int u; } v; v.f = f;
  unsigned int u = v.u;
  u += 0x7FFFu + ((u >> 16) & 1u);
  return (u16)(u >> 16);
}
__device__ __forceinline__ unsigned fbits(float f){
  union { float f; unsigned u; } v; v.f = f; return v.u;
}
// async global->LDS, 16B per lane; LDS dest = wave-uniform base + lane*16
__device__ __forceinline__ void gld_lds16(const u16* g, u16* l){
  __builtin_amdgcn_global_load_lds((const __attribute__((address_space(1))) unsigned int*)g,
                                   (__attribute__((address_space(3))) unsigned int*)l, 16, 0, 0);
}

// ---------- prep: weight transposes + LayerNorm + rk0, one dispatch ----------
// grid (257, 32), block (32,8):
//   bx<96: Wqkv-T ; 96..127: Wo-T ; bx==128: rk0 = r@Wr (n range by*32..+32) ; bx>=129: LN row
__global__ __launch_bounds__(256) void prep_k(const float* __restrict__ Wqkv, u16* __restrict__ wqkvT,
                                              const float* __restrict__ Wo, u16* __restrict__ woT,
                                              const float* __restrict__ r, const float* __restrict__ Wr,
                                              float* __restrict__ rk0,
                                              const float* __restrict__ x, const float* __restrict__ gw,
                                              const float* __restrict__ bw, u16* __restrict__ xnb){
  __shared__ float tile[32][33];
  __shared__ float red[8];
  const int tx = threadIdx.x, ty = threadIdx.y;
  const int t = ty * 32 + tx;
  if(blockIdx.x == 128){
    // rk0[n] = sum_d r[d] * Wr[d*1024+n]
    const int n = blockIdx.y * 32 + (t & 31);
    const int chunk = t >> 5;                 // 8 chunks of 128 d
    float acc = 0.f;
    const int d0 = chunk * 128;
    for(int d = d0; d < d0 + 128; ++d)
      acc += r[d] * Wr[(size_t)d * 1024 + n];
    tile[chunk][t & 31] = acc;
    __syncthreads();
    if(chunk == 0){
      float s = 0.f;
      #pragma unroll
      for(int c = 0; c < 8; ++c) s += tile[c][t & 31];
      rk0[n] = s;
    }
    return;
  }
  if(blockIdx.x >= 129){
    const int row = (blockIdx.x - 129) * 32 + blockIdx.y;
    const float* xr = x + (size_t)row * 1024;
    float4 xv = *reinterpret_cast<const float4*>(xr + t * 4);
    float s  = xv.x + xv.y + xv.z + xv.w;
    float s2 = xv.x*xv.x + xv.y*xv.y + xv.z*xv.z + xv.w*xv.w;
    #pragma unroll
    for(int m = 1; m <= 32; m <<= 1){ s += __shfl_xor(s, m, 64); s2 += __shfl_xor(s2, m, 64); }
    const int w = t >> 6, lane = t & 63;
    if(lane == 0){ red[w] = s; red[4 + w] = s2; }
    __syncthreads();
    float S1 = red[0] + red[1] + red[2] + red[3];
    float S2 = red[4] + red[5] + red[6] + red[7];
    float mu = S1 * (1.f/1024.f);
    float var = S2 * (1.f/1024.f) - mu * mu;
    float rstd = rsqrtf(var + 1e-5f);
    float4 gv = *reinterpret_cast<const float4*>(gw + t * 4);
    float4 bv = *reinterpret_cast<const float4*>(bw + t * 4);
    ushort4 o;
    o.x = f2bf((xv.x - mu) * rstd * gv.x + bv.x);
    o.y = f2bf((xv.y - mu) * rstd * gv.y + bv.y);
    o.z = f2bf((xv.z - mu) * rstd * gv.z + bv.z);
    o.w = f2bf((xv.w - mu) * rstd * gv.w + bv.w);
    *reinterpret_cast<ushort4*>(xnb + (size_t)row * 1024 + t * 4) = o;
    return;
  }
  const float* in; u16* out; int C, bxx;
  if(blockIdx.x < 96){ in = Wqkv; out = wqkvT; C = 3072; bxx = blockIdx.x; }
  else               { in = Wo;   out = woT;   C = 1024; bxx = blockIdx.x - 96; }
  const int bx = bxx * 32, by = blockIdx.y * 32;
  #pragma unroll
  for(int i = 0; i < 32; i += 8)
    tile[ty + i][tx] = in[(size_t)(by + ty + i) * C + bx + tx];
  __syncthreads();
  #pragma unroll
  for(int i = 0; i < 32; i += 8)
    out[(size_t)(bx + ty + i) * 1024 + by + tx] = f2bf(tile[tx][ty + i]);
}

// ---------- GEMM1 qkv: BK=64; epilogue: bx<16 -> qk ; bx>=16 -> vT via LDS transpose ----------
__global__ __launch_bounds__(256) void gemm_qkv_k(const u16* __restrict__ A, const u16* __restrict__ BT,
                                                  u16* __restrict__ Cb, u16* __restrict__ vT){
  __shared__ u16 sA[2][128 * 32];
  __shared__ u16 sB[2][128 * 32];
  __shared__ u16 tl[128 * 66];          // v epilogue transpose tile (64 cols + 2 pad)
  const int t = threadIdx.x;
  const int row0 = blockIdx.y * 128, col0 = blockIdx.x * 128;
  const int w = t >> 6, lane = t & 63, g = lane >> 4, lq = lane & 15;
  const int wr = (w >> 1) * 64, wc = (w & 1) * 64;
  const int K = 1024;
  f32x4 zero4 = {0.f, 0.f, 0.f, 0.f};
  f32x4 acc[4][4];
  #pragma unroll
  for(int mi = 0; mi < 4; ++mi)
    #pragma unroll
    for(int ni = 0; ni < 4; ++ni) acc[mi][ni] = zero4;

  for(int kt = 0; kt < K; kt += 64){
    #pragma unroll
    for(int ks = 0; ks < 2; ++ks){
      const int kk = kt + ks * 32;
      gld_lds16(A  + (size_t)(row0 +      (t >> 2)) * K + kk + (t & 3) * 8, &sA[ks][w * 512]);
      gld_lds16(A  + (size_t)(row0 + 64 + (t >> 2)) * K + kk + (t & 3) * 8, &sA[ks][2048 + w * 512]);
      gld_lds16(BT + (size_t)(col0 +      (t >> 2)) * K + kk + (t & 3) * 8, &sB[ks][w * 512]);
      gld_lds16(BT + (size_t)(col0 + 64 + (t >> 2)) * K + kk + (t & 3) * 8, &sB[ks][2048 + w * 512]);
    }
    __syncthreads();
    #pragma unroll
    for(int ks = 0; ks < 2; ++ks){
      bf16x8 af[4];
      #pragma unroll
      for(int mi = 0; mi < 4; ++mi)
        af[mi] = *reinterpret_cast<const bf16x8*>(&sA[ks][(wr + mi * 16 + lq) * 32 + g * 8]);
      #pragma unroll
      for(int ni = 0; ni < 4; ++ni){
        bf16x8 bfr = *reinterpret_cast<const bf16x8*>(&sB[ks][(wc + ni * 16 + lq) * 32 + g * 8]);
        #pragma unroll
        for(int mi = 0; mi < 4; ++mi)
          acc[mi][ni] = __builtin_amdgcn_mfma_f32_16x16x32_bf16(af[mi], bfr, acc[mi][ni], 0, 0, 0);
      }
    }
    __syncthreads();
  }
  if(blockIdx.x < 16){
    #pragma unroll
    for(int mi = 0; mi < 4; ++mi)
      #pragma unroll
      for(int ni = 0; ni < 4; ++ni)
        #pragma unroll
        for(int rg = 0; rg < 4; ++rg){
          const int row = row0 + wr + mi * 16 + g * 4 + rg;
          const int col = col0 + wc + ni * 16 + lq;
          Cb[(size_t)row * 2048 + col] = f2bf(acc[mi][ni][rg]);
        }
  } else {
    // v: write vT[(b*16+h)*64+d][i] via LDS transpose, two 64-col halves (one head each)
    const int cv0 = col0 - 2048;          // multiple of 128 -> heads cv0/64, cv0/64+1
    #pragma unroll
    for(int half = 0; half < 2; ++half){
      if((w & 1) == half){                // this wave's cols live in this half
        #pragma unroll
        for(int mi = 0; mi < 4; ++mi)
          #pragma unroll
          for(int ni = 0; ni < 4; ++ni)
            #pragma unroll
            for(int rg = 0; rg < 4; ++rg)
              tl[(wr + mi * 16 + g * 4 + rg) * 66 + ni * 16 + lq] = f2bf(acc[mi][ni][rg]);
      }
      __syncthreads();
      const int h = (cv0 >> 6) + half;
      const int b2 = w >> 1, dup = w & 1, d = lane;   // wave-uniform (b2,dup), lane = d
      const int R = (b2 * 16 + h) * 64 + d;
      u16 tmp[32];
      #pragma unroll
      for(int e = 0; e < 32; ++e)
        tmp[e] = tl[((dup * 32 + e) * 2 + b2) * 66 + d];
      u16* op = vT + (size_t)R * 2048 + (row0 >> 1) + dup * 32;
      *reinterpret_cast<u16x8*>(op)      = *reinterpret_cast<u16x8*>(&tmp[0]);
      *reinterpret_cast<u16x8*>(op + 8)  = *reinterpret_cast<u16x8*>(&tmp[8]);
      *reinterpret_cast<u16x8*>(op + 16) = *reinterpret_cast<u16x8*>(&tmp[16]);
      *reinterpret_cast<u16x8*>(op + 24) = *reinterpret_cast<u16x8*>(&tmp[24]);
      __syncthreads();
    }
  }
}

// ---------- GEMM2 out: f32 = av @ woT^T + residual ----------
__global__ __launch_bounds__(256) void gemm_out_k(const u16* __restrict__ A, const u16* __restrict__ BT,
                                                  const u16* __restrict__ res, float* __restrict__ Cf){
  __shared__ u16 sA[128 * 32];
  __shared__ u16 sB[64 * 32];
  const int t = threadIdx.x;
  const int row0 = blockIdx.y * 128, col0 = blockIdx.x * 64;
  const int w = t >> 6, lane = t & 63, g = lane >> 4, lq = lane & 15;
  const int wr = (w >> 1) * 64, wc = (w & 1) * 32;
  const int K = 1024, N = 1024;
  f32x4 zero4 = {0.f, 0.f, 0.f, 0.f};
  f32x4 acc[4][2];
  #pragma unroll
  for(int mi = 0; mi < 4; ++mi)
    #pragma unroll
    for(int ni = 0; ni < 2; ++ni) acc[mi][ni] = zero4;

  for(int kt = 0; kt < K; kt += 32){
    gld_lds16(A  + (size_t)(row0 +      (t >> 2)) * K + kt + (t & 3) * 8, &sA[w * 512]);
    gld_lds16(A  + (size_t)(row0 + 64 + (t >> 2)) * K + kt + (t & 3) * 8, &sA[2048 + w * 512]);
    gld_lds16(BT + (size_t)(col0 +      (t >> 2)) * K + kt + (t & 3) * 8, &sB[w * 512]);
    __syncthreads();
    bf16x8 af[4];
    #pragma unroll
    for(int mi = 0; mi < 4; ++mi)
      af[mi] = *reinterpret_cast<const bf16x8*>(&sA[(wr + mi * 16 + lq) * 32 + g * 8]);
    #pragma unroll
    for(int ni = 0; ni < 2; ++ni){
      bf16x8 bfr = *reinterpret_cast<const bf16x8*>(&sB[(wc + ni * 16 + lq) * 32 + g * 8]);
      #pragma unroll
      for(int mi = 0; mi < 4; ++mi)
        acc[mi][ni] = __builtin_amdgcn_mfma_f32_16x16x32_bf16(af[mi], bfr, acc[mi][ni], 0, 0, 0);
    }
    __syncthreads();
  }
  #pragma unroll
  for(int mi = 0; mi < 4; ++mi)
    #pragma unroll
    for(int ni = 0; ni < 2; ++ni)
      #pragma unroll
      for(int rg = 0; rg < 4; ++rg){
        const int row = row0 + wr + mi * 16 + g * 4 + rg;
        const int col = col0 + wc + ni * 16 + lq;
        Cf[(size_t)row * N + col] = acc[mi][ni][rg] + bf2f(res[(size_t)row * N + col]);
      }
}

// ---------- flash attention: 32x32x16, S^T form, shfl-exchange P, inline BD dot ----------
// grid: (S/128, B*H); block 512 = 8 waves. Wave w: qw=w>>1 owns 32 q-rows [i0+32qw,+32);
// kw=w&1 splits keys by 64-tile parity (kw=0 even tiles, kw=1 odd). Partial (acc,rsum)
// combine by addition at the end (no-max streaming softmax -> exact). Doubles waves/SIMD
// from 2 to 4 to attack the latency-bound profile (MfmaUtil 19.5 / VALUBusy 50 / Occ 18).
__global__ __launch_bounds__(512, 4) void attn_k(const u16* __restrict__ qk, const u16* __restrict__ vT,
                                                 const float* __restrict__ rw, const float* __restrict__ rr,
                                                 const float* __restrict__ rk0, u16* __restrict__ av){
  constexpr int S = 2048, ST = 74;  // 37-dword row stride: 2-way bank aliasing only (free)
  __shared__ u16 smem[4][64 * ST];  // [0],[1]=K parity bufs; [2],[3]=V parity bufs; also combine scratch
  const int t = threadIdx.x;
  const int i0 = blockIdx.x * 128;
  const int bh = blockIdx.y;
  const int b = bh >> 4, h = bh & 15;
  const int w = t >> 6, lane = t & 63, m = lane & 31, q5 = lane >> 5;
  const int qw = w >> 1, kw = w & 1;
  const int iw0 = i0 + qw * 32;
  const int i_lane = iw0 + m;
  const float SC = 0.125f * 1.4426950408889634f;

  // Q B-frags + inline BD dots: ci = sum_d (q[i]+rr)*rk0, cp = same for row i+1
  bf16x8 qf[4];
  float ciL, cpL;
  {
    const bool hasnext = (i_lane + 1 < S);
    const u16* qp  = qk + (size_t)(i_lane * 2 + b) * 2048 + h * 64;
    const u16* qp2 = qk + (size_t)((hasnext ? i_lane + 1 : i_lane) * 2 + b) * 2048 + h * 64;
    const float* rwp = rw  + h * 64;
    const float* rrp = rr  + h * 64;
    const float* rkp = rk0 + h * 64;
    float cpart = 0.f, cppart = 0.f;
    #pragma unroll
    for(int kt = 0; kt < 4; ++kt){
      const int dbase = kt * 16 + q5 * 8;
      u16x8 qv  = *reinterpret_cast<const u16x8*>(qp  + dbase);
      u16x8 qv2 = *reinterpret_cast<const u16x8*>(qp2 + dbase);
      u16x8 a;
      #pragma unroll
      for(int e = 0; e < 8; ++e){
        const float qe  = bf2f(qv[e]);
        const float rke = rkp[dbase + e];
        const float rre = rrp[dbase + e];
        a[e] = f2bf((qe + rwp[dbase + e]) * SC);
        cpart  += (qe + rre) * rke;
        cppart += (bf2f(qv2[e]) + rre) * rke;
      }
      qf[kt] = *reinterpret_cast<bf16x8*>(&a);
    }
    cpart  += __shfl_xor(cpart, 32, 64);   // partner lane holds the other 32 d
    cppart += __shfl_xor(cppart, 32, 64);
    ciL = cpart * SC;
    cpL = hasnext ? cppart * SC : 0.0f;
  }

  f32x16 acc0, acc1, z16;
  #pragma unroll
  for(int e = 0; e < 16; ++e) z16[e] = 0.f;
  acc0 = z16; acc1 = z16;
  float rsum = 0.f;

  // staging: 512 threads stage BOTH parity tiles per iteration (one u16x8 each per tile-load)
  const int jr = t >> 3, c0 = (t & 7) * 8;
  const int lo = jr * ST + c0;
  {
    const u16* kp = qk + (size_t)(jr * 2 + b) * 2048 + 1024 + h * 64 + c0;
    *reinterpret_cast<u16x8*>(&smem[0][lo]) = *reinterpret_cast<const u16x8*>(kp);
    *reinterpret_cast<u16x8*>(&smem[1][lo]) = *reinterpret_cast<const u16x8*>(kp + (size_t)64 * 2 * 2048);
    const u16* vp = vT + ((size_t)bh * 64 + jr) * 2048 + c0;
    *reinterpret_cast<u16x8*>(&smem[2][lo]) = *reinterpret_cast<const u16x8*>(vp);
    *reinterpret_cast<u16x8*>(&smem[3][lo]) = *reinterpret_cast<const u16x8*>(vp + 64);
  }
  __syncthreads();

  const u16* ksb = &smem[kw][0];
  const u16* vsb = &smem[2 + kw][0];

  for(int np = 0; np < 16; ++np){
    u16x8 kE, kO, vE, vO;
    const bool pre = (np + 1 < 16);
    if(pre){
      const int j0n = (2 * np + 2) * 64;
      const u16* kp = qk + (size_t)((j0n + jr) * 2 + b) * 2048 + 1024 + h * 64 + c0;
      kE = *reinterpret_cast<const u16x8*>(kp);
      kO = *reinterpret_cast<const u16x8*>(kp + (size_t)64 * 2 * 2048);
      const u16* vp = vT + ((size_t)bh * 64 + jr) * 2048 + j0n + c0;
      vE = *reinterpret_cast<const u16x8*>(vp);
      vO = *reinterpret_cast<const u16x8*>(vp + 64);
    }
    const int j0 = (2 * np + kw) * 64;
    bf16x8 pfrag[4];
    #pragma unroll
    for(int jt = 0; jt < 2; ++jt){
      const int tj0 = j0 + jt * 32;
      f32x16 s = z16;
      #pragma unroll
      for(int kt = 0; kt < 4; ++kt){
        bf16x8 ka = *reinterpret_cast<const bf16x8*>(&ksb[(jt * 32 + m) * ST + kt * 16 + q5 * 8]);
        s = __builtin_amdgcn_mfma_f32_32x32x16_bf16(ka, qf[kt], s, 0, 0, 0);
      }
      float pv[16];
      if(tj0 + 31 <= iw0){
        #pragma unroll
        for(int r2 = 0; r2 < 16; ++r2) pv[r2] = __builtin_amdgcn_exp2f(s[r2] + ciL);
      } else if(tj0 >= iw0 + 33){
        #pragma unroll
        for(int r2 = 0; r2 < 16; ++r2) pv[r2] = __builtin_amdgcn_exp2f(s[r2] + cpL);
      } else {
        #pragma unroll
        for(int r2 = 0; r2 < 16; ++r2){
          const int j = tj0 + (r2 & 3) + 8 * (r2 >> 2) + 4 * q5;
          const float t1 = (j <= i_lane) ? ciL : cpL;
          const float bdL = (j == i_lane + 1) ? 0.0f : t1;
          pv[r2] = __builtin_amdgcn_exp2f(s[r2] + bdL);
        }
      }
      #pragma unroll
      for(int r2 = 0; r2 < 16; ++r2) rsum += pv[r2];
      unsigned pk[8];
      #pragma unroll
      for(int q = 0; q < 8; ++q)
        pk[q] = __builtin_amdgcn_perm(fbits(pv[2 * q + 1]), fbits(pv[2 * q]), 0x07060302);
      unsigned sAx = (q5 == 0) ? pk[2] : pk[0];
      unsigned sAy = (q5 == 0) ? pk[3] : pk[1];
      unsigned rAx = (unsigned)__shfl_xor((int)sAx, 32, 64);
      unsigned rAy = (unsigned)__shfl_xor((int)sAy, 32, 64);
      unsigned sBx = (q5 == 0) ? pk[6] : pk[4];
      unsigned sBy = (q5 == 0) ? pk[7] : pk[5];
      unsigned rBx = (unsigned)__shfl_xor((int)sBx, 32, 64);
      unsigned rBy = (unsigned)__shfl_xor((int)sBy, 32, 64);
      union { unsigned u[4]; bf16x8 bf; } f0, f1;
      if(q5 == 0){
        f0.u[0] = pk[0]; f0.u[1] = pk[1]; f0.u[2] = rAx; f0.u[3] = rAy;
        f1.u[0] = pk[4]; f1.u[1] = pk[5]; f1.u[2] = rBx; f1.u[3] = rBy;
      } else {
        f0.u[0] = rAx; f0.u[1] = rAy; f0.u[2] = pk[2]; f0.u[3] = pk[3];
        f1.u[0] = rBx; f1.u[1] = rBy; f1.u[2] = pk[6]; f1.u[3] = pk[7];
      }
      pfrag[jt * 2 + 0] = f0.bf;
      pfrag[jt * 2 + 1] = f1.bf;
    }
    #pragma unroll
    for(int kt = 0; kt < 4; ++kt){
      bf16x8 va0 = *reinterpret_cast<const bf16x8*>(&vsb[(m) * ST + kt * 16 + q5 * 8]);
      acc0 = __builtin_amdgcn_mfma_f32_32x32x16_bf16(va0, pfrag[kt], acc0, 0, 0, 0);
      bf16x8 va1 = *reinterpret_cast<const bf16x8*>(&vsb[(32 + m) * ST + kt * 16 + q5 * 8]);
      acc1 = __builtin_amdgcn_mfma_f32_32x32x16_bf16(va1, pfrag[kt], acc1, 0, 0, 0);
    }
    __syncthreads();   // all waves done reading both parity buffers
    if(pre){
      *reinterpret_cast<u16x8*>(&smem[0][lo]) = kE;
      *reinterpret_cast<u16x8*>(&smem[1][lo]) = kO;
      *reinterpret_cast<u16x8*>(&smem[2][lo]) = vE;
      *reinterpret_cast<u16x8*>(&smem[3][lo]) = vO;
    }
    __syncthreads();   // staged for next iteration
  }

  rsum += __shfl_xor(rsum, 32, 64);

  // cross-parity combine: kw=1 writes partial (acc,rsum) to LDS; kw=0 adds + stores.
  // region: 4 qw-groups x 64 lanes x 33 f32 = 33792 B <= 37888 B of smem. stride 33 -> no conflicts.
  float* com = reinterpret_cast<float*>(&smem[0][0]) + (size_t)(qw * 64 + lane) * 33;
  if(kw == 1){
    #pragma unroll
    for(int e = 0; e < 16; ++e) com[e] = acc0[e];
    #pragma unroll
    for(int e = 0; e < 16; ++e) com[16 + e] = acc1[e];
    com[32] = rsum;
  }
  __syncthreads();
  if(kw == 0){
    #pragma unroll
    for(int e = 0; e < 16; ++e) acc0[e] += com[e];
    #pragma unroll
    for(int e = 0; e < 16; ++e) acc1[e] += com[16 + e];
    rsum += com[32];
    const float rinv = 1.0f / rsum;
    u16* op = av + (size_t)(i_lane * 2 + b) * 1024 + h * 64;
    #pragma unroll
    for(int dt = 0; dt < 2; ++dt){
      const f32x16& A = dt ? acc1 : acc0;
      #pragma unroll
      for(int rq = 0; rq < 4; ++rq){
        ushort4 o;
        o.x = f2bf(A[rq * 4 + 0] * rinv);
        o.y = f2bf(A[rq * 4 + 1] * rinv);
        o.z = f2bf(A[rq * 4 + 2] * rinv);
        o.w = f2bf(A[rq * 4 + 3] * rinv);
        const int d0 = dt * 32 + 8 * rq + 4 * q5;
        *reinterpret_cast<ushort4*>(op + d0) = o;
      }
    }
  }
}

extern "C" void kernel_launch(void* const* d_in, const int* in_sizes, int n_in,
                              void* d_out, int out_size, void* d_ws, size_t ws_size,
                              hipStream_t stream){
  (void)in_sizes; (void)n_in; (void)out_size; (void)ws_size;
  const float* x    = (const float*)d_in[0];
  const float* r    = (const float*)d_in[1];
  const float* rw   = (const float*)d_in[2];
  const float* rr   = (const float*)d_in[3];
  const float* ln_g = (const float*)d_in[4];
  const float* ln_b = (const float*)d_in[5];
  const float* Wqkv = (const float*)d_in[6];
  const float* Wr   = (const float*)d_in[7];
  const float* Wo   = (const float*)d_in[8];
  char* ws = (char*)d_ws;
  u16*   xnb   = (u16*)(ws + 0);                    //  8 MB bf16 [4096,1024]
  u16*   qk    = (u16*)(ws + 8388608);              // 16 MB bf16 [4096,2048] (q | k)
  u16*   av    = (u16*)(ws + 25165824);             //  8 MB bf16 [4096,1024]
  u16*   woT   = (u16*)(ws + 33554432);             //  2 MB bf16 [1024,1024]
  u16*   wqkvT = (u16*)(ws + 35651584);             //  6 MB bf16 [3072,1024]
  u16*   vT    = (u16*)(ws + 41943040);             //  8 MB bf16 [32,64,2048]
  float* rk0   = (float*)(ws + 50331648);           //  4 KB f32 [1024]
  float* out   = (float*)d_out;

  prep_k<<<dim3(257, 32), dim3(32, 8), 0, stream>>>(Wqkv, wqkvT, Wo, woT, r, Wr, rk0,
                                                    x, ln_g, ln_b, xnb);
  gemm_qkv_k<<<dim3(24, 32), 256, 0, stream>>>(xnb, wqkvT, qk, vT);
  attn_k<<<dim3(16, 32), 512, 0, stream>>>(qk, vT, rw, rr, rk0, av);
  gemm_out_k<<<dim3(16, 32), 256, 0, stream>>>(av, woT, xnb, out);
}

// Round 2
// 301.170 us; speedup vs baseline: 1.0469x; 1.0469x over previous
//
#include <hip/hip_runtime.h>

typedef unsigned short u16;
typedef __attribute__((ext_vector_type(8))) __bf16 bf16x8;
typedef __attribute__((ext_vector_type(8))) u16 u16x8;
typedef __attribute__((ext_vector_type(4))) float f32x4;
typedef __attribute__((ext_vector_type(16))) float f32x16;

__device__ __forceinline__ float bf2f(u16 u){
  union { unsigned int i; float f; } v; v.i = ((unsigned int)u) << 16; return v.f;
}
__device__ __forceinline__ u16 f2bf(float f){
  union { float f; unsigned int u; } v; v.f = f;
  unsigned int u = v.u;
  u += 0x7FFFu + ((u >> 16) & 1u);
  return (u16)(u >> 16);
}
__device__ __forceinline__ unsigned fbits(float f){
  union { float f; unsigned u; } v; v.f = f; return v.u;
}
// async global->LDS, 16B per lane; LDS dest = wave-uniform base + lane*16
__device__ __forceinline__ void gld_lds16(const u16* g, u16* l){
  __builtin_amdgcn_global_load_lds((const __attribute__((address_space(1))) unsigned int*)g,
                                   (__attribute__((address_space(3))) unsigned int*)l, 16, 0, 0);
}

// ---------- prep: weight transposes + LayerNorm + rk0, one dispatch ----------
// grid (257, 32), block (32,8):
//   bx<96: Wqkv-T ; 96..127: Wo-T ; bx==128: rk0 = r@Wr (n range by*32..+32) ; bx>=129: LN row
__global__ __launch_bounds__(256) void prep_k(const float* __restrict__ Wqkv, u16* __restrict__ wqkvT,
                                              const float* __restrict__ Wo, u16* __restrict__ woT,
                                              const float* __restrict__ r, const float* __restrict__ Wr,
                                              float* __restrict__ rk0,
                                              const float* __restrict__ x, const float* __restrict__ gw,
                                              const float* __restrict__ bw, u16* __restrict__ xnb){
  __shared__ float tile[32][33];
  __shared__ float red[8];
  const int tx = threadIdx.x, ty = threadIdx.y;
  const int t = ty * 32 + tx;
  if(blockIdx.x == 128){
    // rk0[n] = sum_d r[d] * Wr[d*1024+n]
    const int n = blockIdx.y * 32 + (t & 31);
    const int chunk = t >> 5;                 // 8 chunks of 128 d
    float acc = 0.f;
    const int d0 = chunk * 128;
    for(int d = d0; d < d0 + 128; ++d)
      acc += r[d] * Wr[(size_t)d * 1024 + n];
    tile[chunk][t & 31] = acc;
    __syncthreads();
    if(chunk == 0){
      float s = 0.f;
      #pragma unroll
      for(int c = 0; c < 8; ++c) s += tile[c][t & 31];
      rk0[n] = s;
    }
    return;
  }
  if(blockIdx.x >= 129){
    const int row = (blockIdx.x - 129) * 32 + blockIdx.y;
    const float* xr = x + (size_t)row * 1024;
    float4 xv = *reinterpret_cast<const float4*>(xr + t * 4);
    float s  = xv.x + xv.y + xv.z + xv.w;
    float s2 = xv.x*xv.x + xv.y*xv.y + xv.z*xv.z + xv.w*xv.w;
    #pragma unroll
    for(int m = 1; m <= 32; m <<= 1){ s += __shfl_xor(s, m, 64); s2 += __shfl_xor(s2, m, 64); }
    const int w = t >> 6, lane = t & 63;
    if(lane == 0){ red[w] = s; red[4 + w] = s2; }
    __syncthreads();
    float S1 = red[0] + red[1] + red[2] + red[3];
    float S2 = red[4] + red[5] + red[6] + red[7];
    float mu = S1 * (1.f/1024.f);
    float var = S2 * (1.f/1024.f) - mu * mu;
    float rstd = rsqrtf(var + 1e-5f);
    float4 gv = *reinterpret_cast<const float4*>(gw + t * 4);
    float4 bv = *reinterpret_cast<const float4*>(bw + t * 4);
    ushort4 o;
    o.x = f2bf((xv.x - mu) * rstd * gv.x + bv.x);
    o.y = f2bf((xv.y - mu) * rstd * gv.y + bv.y);
    o.z = f2bf((xv.z - mu) * rstd * gv.z + bv.z);
    o.w = f2bf((xv.w - mu) * rstd * gv.w + bv.w);
    *reinterpret_cast<ushort4*>(xnb + (size_t)row * 1024 + t * 4) = o;
    return;
  }
  const float* in; u16* out; int C, bxx;
  if(blockIdx.x < 96){ in = Wqkv; out = wqkvT; C = 3072; bxx = blockIdx.x; }
  else               { in = Wo;   out = woT;   C = 1024; bxx = blockIdx.x - 96; }
  const int bx = bxx * 32, by = blockIdx.y * 32;
  #pragma unroll
  for(int i = 0; i < 32; i += 8)
    tile[ty + i][tx] = in[(size_t)(by + ty + i) * C + bx + tx];
  __syncthreads();
  #pragma unroll
  for(int i = 0; i < 32; i += 8)
    out[(size_t)(bx + ty + i) * 1024 + by + tx] = f2bf(tile[tx][ty + i]);
}

// ---------- GEMM1 qkv: BK=64; epilogue: bx<16 -> qk ; bx>=16 -> vT via LDS transpose ----------
__global__ __launch_bounds__(256) void gemm_qkv_k(const u16* __restrict__ A, const u16* __restrict__ BT,
                                                  u16* __restrict__ Cb, u16* __restrict__ vT){
  __shared__ u16 sA[2][128 * 32];
  __shared__ u16 sB[2][128 * 32];
  __shared__ u16 tl[128 * 66];          // v epilogue transpose tile (64 cols + 2 pad)
  const int t = threadIdx.x;
  const int row0 = blockIdx.y * 128, col0 = blockIdx.x * 128;
  const int w = t >> 6, lane = t & 63, g = lane >> 4, lq = lane & 15;
  const int wr = (w >> 1) * 64, wc = (w & 1) * 64;
  const int K = 1024;
  f32x4 zero4 = {0.f, 0.f, 0.f, 0.f};
  f32x4 acc[4][4];
  #pragma unroll
  for(int mi = 0; mi < 4; ++mi)
    #pragma unroll
    for(int ni = 0; ni < 4; ++ni) acc[mi][ni] = zero4;

  for(int kt = 0; kt < K; kt += 64){
    #pragma unroll
    for(int ks = 0; ks < 2; ++ks){
      const int kk = kt + ks * 32;
      gld_lds16(A  + (size_t)(row0 +      (t >> 2)) * K + kk + (t & 3) * 8, &sA[ks][w * 512]);
      gld_lds16(A  + (size_t)(row0 + 64 + (t >> 2)) * K + kk + (t & 3) * 8, &sA[ks][2048 + w * 512]);
      gld_lds16(BT + (size_t)(col0 +      (t >> 2)) * K + kk + (t & 3) * 8, &sB[ks][w * 512]);
      gld_lds16(BT + (size_t)(col0 + 64 + (t >> 2)) * K + kk + (t & 3) * 8, &sB[ks][2048 + w * 512]);
    }
    __syncthreads();
    #pragma unroll
    for(int ks = 0; ks < 2; ++ks){
      bf16x8 af[4];
      #pragma unroll
      for(int mi = 0; mi < 4; ++mi)
        af[mi] = *reinterpret_cast<const bf16x8*>(&sA[ks][(wr + mi * 16 + lq) * 32 + g * 8]);
      #pragma unroll
      for(int ni = 0; ni < 4; ++ni){
        bf16x8 bfr = *reinterpret_cast<const bf16x8*>(&sB[ks][(wc + ni * 16 + lq) * 32 + g * 8]);
        #pragma unroll
        for(int mi = 0; mi < 4; ++mi)
          acc[mi][ni] = __builtin_amdgcn_mfma_f32_16x16x32_bf16(af[mi], bfr, acc[mi][ni], 0, 0, 0);
      }
    }
    __syncthreads();
  }
  if(blockIdx.x < 16){
    #pragma unroll
    for(int mi = 0; mi < 4; ++mi)
      #pragma unroll
      for(int ni = 0; ni < 4; ++ni)
        #pragma unroll
        for(int rg = 0; rg < 4; ++rg){
          const int row = row0 + wr + mi * 16 + g * 4 + rg;
          const int col = col0 + wc + ni * 16 + lq;
          Cb[(size_t)row * 2048 + col] = f2bf(acc[mi][ni][rg]);
        }
  } else {
    // v: write vT[(b*16+h)*64+d][i] via LDS transpose, two 64-col halves (one head each)
    const int cv0 = col0 - 2048;          // multiple of 128 -> heads cv0/64, cv0/64+1
    #pragma unroll
    for(int half = 0; half < 2; ++half){
      if((w & 1) == half){                // this wave's cols live in this half
        #pragma unroll
        for(int mi = 0; mi < 4; ++mi)
          #pragma unroll
          for(int ni = 0; ni < 4; ++ni)
            #pragma unroll
            for(int rg = 0; rg < 4; ++rg)
              tl[(wr + mi * 16 + g * 4 + rg) * 66 + ni * 16 + lq] = f2bf(acc[mi][ni][rg]);
      }
      __syncthreads();
      const int h = (cv0 >> 6) + half;
      const int b2 = w >> 1, dup = w & 1, d = lane;   // wave-uniform (b2,dup), lane = d
      const int R = (b2 * 16 + h) * 64 + d;
      u16 tmp[32];
      #pragma unroll
      for(int e = 0; e < 32; ++e)
        tmp[e] = tl[((dup * 32 + e) * 2 + b2) * 66 + d];
      u16* op = vT + (size_t)R * 2048 + (row0 >> 1) + dup * 32;
      *reinterpret_cast<u16x8*>(op)      = *reinterpret_cast<u16x8*>(&tmp[0]);
      *reinterpret_cast<u16x8*>(op + 8)  = *reinterpret_cast<u16x8*>(&tmp[8]);
      *reinterpret_cast<u16x8*>(op + 16) = *reinterpret_cast<u16x8*>(&tmp[16]);
      *reinterpret_cast<u16x8*>(op + 24) = *reinterpret_cast<u16x8*>(&tmp[24]);
      __syncthreads();
    }
  }
}

// ---------- GEMM2 out: f32 = av @ woT^T + residual ----------
__global__ __launch_bounds__(256) void gemm_out_k(const u16* __restrict__ A, const u16* __restrict__ BT,
                                                  const u16* __restrict__ res, float* __restrict__ Cf){
  __shared__ u16 sA[128 * 32];
  __shared__ u16 sB[64 * 32];
  const int t = threadIdx.x;
  const int row0 = blockIdx.y * 128, col0 = blockIdx.x * 64;
  const int w = t >> 6, lane = t & 63, g = lane >> 4, lq = lane & 15;
  const int wr = (w >> 1) * 64, wc = (w & 1) * 32;
  const int K = 1024, N = 1024;
  f32x4 zero4 = {0.f, 0.f, 0.f, 0.f};
  f32x4 acc[4][2];
  #pragma unroll
  for(int mi = 0; mi < 4; ++mi)
    #pragma unroll
    for(int ni = 0; ni < 2; ++ni) acc[mi][ni] = zero4;

  for(int kt = 0; kt < K; kt += 32){
    gld_lds16(A  + (size_t)(row0 +      (t >> 2)) * K + kt + (t & 3) * 8, &sA[w * 512]);
    gld_lds16(A  + (size_t)(row0 + 64 + (t >> 2)) * K + kt + (t & 3) * 8, &sA[2048 + w * 512]);
    gld_lds16(BT + (size_t)(col0 +      (t >> 2)) * K + kt + (t & 3) * 8, &sB[w * 512]);
    __syncthreads();
    bf16x8 af[4];
    #pragma unroll
    for(int mi = 0; mi < 4; ++mi)
      af[mi] = *reinterpret_cast<const bf16x8*>(&sA[(wr + mi * 16 + lq) * 32 + g * 8]);
    #pragma unroll
    for(int ni = 0; ni < 2; ++ni){
      bf16x8 bfr = *reinterpret_cast<const bf16x8*>(&sB[(wc + ni * 16 + lq) * 32 + g * 8]);
      #pragma unroll
      for(int mi = 0; mi < 4; ++mi)
        acc[mi][ni] = __builtin_amdgcn_mfma_f32_16x16x32_bf16(af[mi], bfr, acc[mi][ni], 0, 0, 0);
    }
    __syncthreads();
  }
  #pragma unroll
  for(int mi = 0; mi < 4; ++mi)
    #pragma unroll
    for(int ni = 0; ni < 2; ++ni)
      #pragma unroll
      for(int rg = 0; rg < 4; ++rg){
        const int row = row0 + wr + mi * 16 + g * 4 + rg;
        const int col = col0 + wc + ni * 16 + lq;
        Cf[(size_t)row * N + col] = acc[mi][ni][rg] + bf2f(res[(size_t)row * N + col]);
      }
}

// ---------- flash attention: 32x32x16, S^T form, shfl-exchange P, inline BD dot ----------
// grid: (S/128, B*H); block 512 = 8 waves. Wave w: qw=w>>1 owns 32 q-rows [i0+32qw,+32);
// kw=w&1 splits keys by 64-tile parity (kw=0 even tiles, kw=1 odd). Partial (acc,rsum)
// combine by addition at the end (no-max streaming softmax -> exact).
// __launch_bounds__(512, 2): 2nd arg is min BLOCKS/CU (CUDA semantics — observed r1:
// arg=4 forced VGPR cap 64 -> massive scratch spill, WRITE_SIZE 4x). 2 blocks/CU ->
// VGPR cap 128, fits the ~112-reg live state, gives 4 waves/SIMD.
__global__ __launch_bounds__(512, 2) void attn_k(const u16* __restrict__ qk, const u16* __restrict__ vT,
                                                 const float* __restrict__ rw, const float* __restrict__ rr,
                                                 const float* __restrict__ rk0, u16* __restrict__ av){
  constexpr int S = 2048, ST = 74;  // 37-dword row stride: 2-way bank aliasing only (free)
  __shared__ u16 smem[4][64 * ST];  // [0],[1]=K parity bufs; [2],[3]=V parity bufs; also combine scratch
  const int t = threadIdx.x;
  const int i0 = blockIdx.x * 128;
  const int bh = blockIdx.y;
  const int b = bh >> 4, h = bh & 15;
  const int w = t >> 6, lane = t & 63, m = lane & 31, q5 = lane >> 5;
  const int qw = w >> 1, kw = w & 1;
  const int iw0 = i0 + qw * 32;
  const int i_lane = iw0 + m;
  const float SC = 0.125f * 1.4426950408889634f;

  // Q B-frags + inline BD dots: ci = sum_d (q[i]+rr)*rk0, cp = same for row i+1
  bf16x8 qf[4];
  float ciL, cpL;
  {
    const bool hasnext = (i_lane + 1 < S);
    const u16* qp  = qk + (size_t)(i_lane * 2 + b) * 2048 + h * 64;
    const u16* qp2 = qk + (size_t)((hasnext ? i_lane + 1 : i_lane) * 2 + b) * 2048 + h * 64;
    const float* rwp = rw  + h * 64;
    const float* rrp = rr  + h * 64;
    const float* rkp = rk0 + h * 64;
    float cpart = 0.f, cppart = 0.f;
    #pragma unroll
    for(int kt = 0; kt < 4; ++kt){
      const int dbase = kt * 16 + q5 * 8;
      u16x8 qv  = *reinterpret_cast<const u16x8*>(qp  + dbase);
      u16x8 qv2 = *reinterpret_cast<const u16x8*>(qp2 + dbase);
      u16x8 a;
      #pragma unroll
      for(int e = 0; e < 8; ++e){
        const float qe  = bf2f(qv[e]);
        const float rke = rkp[dbase + e];
        const float rre = rrp[dbase + e];
        a[e] = f2bf((qe + rwp[dbase + e]) * SC);
        cpart  += (qe + rre) * rke;
        cppart += (bf2f(qv2[e]) + rre) * rke;
      }
      qf[kt] = *reinterpret_cast<bf16x8*>(&a);
    }
    cpart  += __shfl_xor(cpart, 32, 64);   // partner lane holds the other 32 d
    cppart += __shfl_xor(cppart, 32, 64);
    ciL = cpart * SC;
    cpL = hasnext ? cppart * SC : 0.0f;
  }

  f32x16 acc0, acc1, z16;
  #pragma unroll
  for(int e = 0; e < 16; ++e) z16[e] = 0.f;
  acc0 = z16; acc1 = z16;
  float rsum = 0.f;

  // staging: 512 threads stage BOTH parity tiles per iteration (one u16x8 each per tile-load)
  const int jr = t >> 3, c0 = (t & 7) * 8;
  const int lo = jr * ST + c0;
  {
    const u16* kp = qk + (size_t)(jr * 2 + b) * 2048 + 1024 + h * 64 + c0;
    *reinterpret_cast<u16x8*>(&smem[0][lo]) = *reinterpret_cast<const u16x8*>(kp);
    *reinterpret_cast<u16x8*>(&smem[1][lo]) = *reinterpret_cast<const u16x8*>(kp + (size_t)64 * 2 * 2048);
    const u16* vp = vT + ((size_t)bh * 64 + jr) * 2048 + c0;
    *reinterpret_cast<u16x8*>(&smem[2][lo]) = *reinterpret_cast<const u16x8*>(vp);
    *reinterpret_cast<u16x8*>(&smem[3][lo]) = *reinterpret_cast<const u16x8*>(vp + 64);
  }
  __syncthreads();

  const u16* ksb = &smem[kw][0];
  const u16* vsb = &smem[2 + kw][0];

  for(int np = 0; np < 16; ++np){
    u16x8 kE, kO, vE, vO;
    const bool pre = (np + 1 < 16);
    if(pre){
      const int j0n = (2 * np + 2) * 64;
      const u16* kp = qk + (size_t)((j0n + jr) * 2 + b) * 2048 + 1024 + h * 64 + c0;
      kE = *reinterpret_cast<const u16x8*>(kp);
      kO = *reinterpret_cast<const u16x8*>(kp + (size_t)64 * 2 * 2048);
      const u16* vp = vT + ((size_t)bh * 64 + jr) * 2048 + j0n + c0;
      vE = *reinterpret_cast<const u16x8*>(vp);
      vO = *reinterpret_cast<const u16x8*>(vp + 64);
    }
    const int j0 = (2 * np + kw) * 64;
    bf16x8 pfrag[4];
    #pragma unroll
    for(int jt = 0; jt < 2; ++jt){
      const int tj0 = j0 + jt * 32;
      f32x16 s = z16;
      #pragma unroll
      for(int kt = 0; kt < 4; ++kt){
        bf16x8 ka = *reinterpret_cast<const bf16x8*>(&ksb[(jt * 32 + m) * ST + kt * 16 + q5 * 8]);
        s = __builtin_amdgcn_mfma_f32_32x32x16_bf16(ka, qf[kt], s, 0, 0, 0);
      }
      float pv[16];
      if(tj0 + 31 <= iw0){
        #pragma unroll
        for(int r2 = 0; r2 < 16; ++r2) pv[r2] = __builtin_amdgcn_exp2f(s[r2] + ciL);
      } else if(tj0 >= iw0 + 33){
        #pragma unroll
        for(int r2 = 0; r2 < 16; ++r2) pv[r2] = __builtin_amdgcn_exp2f(s[r2] + cpL);
      } else {
        #pragma unroll
        for(int r2 = 0; r2 < 16; ++r2){
          const int j = tj0 + (r2 & 3) + 8 * (r2 >> 2) + 4 * q5;
          const float t1 = (j <= i_lane) ? ciL : cpL;
          const float bdL = (j == i_lane + 1) ? 0.0f : t1;
          pv[r2] = __builtin_amdgcn_exp2f(s[r2] + bdL);
        }
      }
      #pragma unroll
      for(int r2 = 0; r2 < 16; ++r2) rsum += pv[r2];
      unsigned pk[8];
      #pragma unroll
      for(int q = 0; q < 8; ++q)
        pk[q] = __builtin_amdgcn_perm(fbits(pv[2 * q + 1]), fbits(pv[2 * q]), 0x07060302);
      unsigned sAx = (q5 == 0) ? pk[2] : pk[0];
      unsigned sAy = (q5 == 0) ? pk[3] : pk[1];
      unsigned rAx = (unsigned)__shfl_xor((int)sAx, 32, 64);
      unsigned rAy = (unsigned)__shfl_xor((int)sAy, 32, 64);
      unsigned sBx = (q5 == 0) ? pk[6] : pk[4];
      unsigned sBy = (q5 == 0) ? pk[7] : pk[5];
      unsigned rBx = (unsigned)__shfl_xor((int)sBx, 32, 64);
      unsigned rBy = (unsigned)__shfl_xor((int)sBy, 32, 64);
      union { unsigned u[4]; bf16x8 bf; } f0, f1;
      if(q5 == 0){
        f0.u[0] = pk[0]; f0.u[1] = pk[1]; f0.u[2] = rAx; f0.u[3] = rAy;
        f1.u[0] = pk[4]; f1.u[1] = pk[5]; f1.u[2] = rBx; f1.u[3] = rBy;
      } else {
        f0.u[0] = rAx; f0.u[1] = rAy; f0.u[2] = pk[2]; f0.u[3] = pk[3];
        f1.u[0] = rBx; f1.u[1] = rBy; f1.u[2] = pk[6]; f1.u[3] = pk[7];
      }
      pfrag[jt * 2 + 0] = f0.bf;
      pfrag[jt * 2 + 1] = f1.bf;
    }
    #pragma unroll
    for(int kt = 0; kt < 4; ++kt){
      bf16x8 va0 = *reinterpret_cast<const bf16x8*>(&vsb[(m) * ST + kt * 16 + q5 * 8]);
      acc0 = __builtin_amdgcn_mfma_f32_32x32x16_bf16(va0, pfrag[kt], acc0, 0, 0, 0);
      bf16x8 va1 = *reinterpret_cast<const bf16x8*>(&vsb[(32 + m) * ST + kt * 16 + q5 * 8]);
      acc1 = __builtin_amdgcn_mfma_f32_32x32x16_bf16(va1, pfrag[kt], acc1, 0, 0, 0);
    }
    __syncthreads();   // all waves done reading both parity buffers
    if(pre){
      *reinterpret_cast<u16x8*>(&smem[0][lo]) = kE;
      *reinterpret_cast<u16x8*>(&smem[1][lo]) = kO;
      *reinterpret_cast<u16x8*>(&smem[2][lo]) = vE;
      *reinterpret_cast<u16x8*>(&smem[3][lo]) = vO;
    }
    __syncthreads();   // staged for next iteration
  }

  rsum += __shfl_xor(rsum, 32, 64);

  // cross-parity combine: kw=1 writes partial (acc,rsum) to LDS; kw=0 adds + stores.
  // region: 4 qw-groups x 64 lanes x 33 f32 = 33792 B <= 37888 B of smem. stride 33 -> no conflicts.
  float* com = reinterpret_cast<float*>(&smem[0][0]) + (size_t)(qw * 64 + lane) * 33;
  if(kw == 1){
    #pragma unroll
    for(int e = 0; e < 16; ++e) com[e] = acc0[e];
    #pragma unroll
    for(int e = 0; e < 16; ++e) com[16 + e] = acc1[e];
    com[32] = rsum;
  }
  __syncthreads();
  if(kw == 0){
    #pragma unroll
    for(int e = 0; e < 16; ++e) acc0[e] += com[e];
    #pragma unroll
    for(int e = 0; e < 16; ++e) acc1[e] += com[16 + e];
    rsum += com[32];
    const float rinv = 1.0f / rsum;
    u16* op = av + (size_t)(i_lane * 2 + b) * 1024 + h * 64;
    #pragma unroll
    for(int dt = 0; dt < 2; ++dt){
      const f32x16& A = dt ? acc1 : acc0;
      #pragma unroll
      for(int rq = 0; rq < 4; ++rq){
        ushort4 o;
        o.x = f2bf(A[rq * 4 + 0] * rinv);
        o.y = f2bf(A[rq * 4 + 1] * rinv);
        o.z = f2bf(A[rq * 4 + 2] * rinv);
        o.w = f2bf(A[rq * 4 + 3] * rinv);
        const int d0 = dt * 32 + 8 * rq + 4 * q5;
        *reinterpret_cast<ushort4*>(op + d0) = o;
      }
    }
  }
}

extern "C" void kernel_launch(void* const* d_in, const int* in_sizes, int n_in,
                              void* d_out, int out_size, void* d_ws, size_t ws_size,
                              hipStream_t stream){
  (void)in_sizes; (void)n_in; (void)out_size; (void)ws_size;
  const float* x    = (const float*)d_in[0];
  const float* r    = (const float*)d_in[1];
  const float* rw   = (const float*)d_in[2];
  const float* rr   = (const float*)d_in[3];
  const float* ln_g = (const float*)d_in[4];
  const float* ln_b = (const float*)d_in[5];
  const float* Wqkv = (const float*)d_in[6];
  const float* Wr   = (const float*)d_in[7];
  const float* Wo   = (const float*)d_in[8];
  char* ws = (char*)d_ws;
  u16*   xnb   = (u16*)(ws + 0);                    //  8 MB bf16 [4096,1024]
  u16*   qk    = (u16*)(ws + 8388608);              // 16 MB bf16 [4096,2048] (q | k)
  u16*   av    = (u16*)(ws + 25165824);             //  8 MB bf16 [4096,1024]
  u16*   woT   = (u16*)(ws + 33554432);             //  2 MB bf16 [1024,1024]
  u16*   wqkvT = (u16*)(ws + 35651584);             //  6 MB bf16 [3072,1024]
  u16*   vT    = (u16*)(ws + 41943040);             //  8 MB bf16 [32,64,2048]
  float* rk0   = (float*)(ws + 50331648);           //  4 KB f32 [1024]
  float* out   = (float*)d_out;

  prep_k<<<dim3(257, 32), dim3(32, 8), 0, stream>>>(Wqkv, wqkvT, Wo, woT, r, Wr, rk0,
                                                    x, ln_g, ln_b, xnb);
  gemm_qkv_k<<<dim3(24, 32), 256, 0, stream>>>(xnb, wqkvT, qk, vT);
  attn_k<<<dim3(16, 32), 512, 0, stream>>>(qk, vT, rw, rr, rk0, av);
  gemm_out_k<<<dim3(16, 32), 256, 0, stream>>>(av, woT, xnb, out);
}

// Round 3
// 235.226 us; speedup vs baseline: 1.3404x; 1.2803x over previous
//
#include <hip/hip_runtime.h>

typedef unsigned short u16;
typedef __attribute__((ext_vector_type(8))) __bf16 bf16x8;
typedef __attribute__((ext_vector_type(8))) u16 u16x8;
typedef __attribute__((ext_vector_type(4))) float f32x4;
typedef __attribute__((ext_vector_type(16))) float f32x16;

__device__ __forceinline__ float bf2f(u16 u){
  union { unsigned int i; float f; } v; v.i = ((unsigned int)u) << 16; return v.f;
}
__device__ __forceinline__ u16 f2bf(float f){
  union { float f; unsigned int u; } v; v.f = f;
  unsigned int u = v.u;
  u += 0x7FFFu + ((u >> 16) & 1u);
  return (u16)(u >> 16);
}
__device__ __forceinline__ unsigned fbits(float f){
  union { float f; unsigned u; } v; v.f = f; return v.u;
}
// async global->LDS, 16B per lane; LDS dest = wave-uniform base + lane*16
__device__ __forceinline__ void gld_lds16(const u16* g, u16* l){
  __builtin_amdgcn_global_load_lds((const __attribute__((address_space(1))) unsigned int*)g,
                                   (__attribute__((address_space(3))) unsigned int*)l, 16, 0, 0);
}

// ---------- prep: weight transposes + LayerNorm + rk0, one dispatch ----------
// grid (257, 32), block (32,8):
//   bx<96: Wqkv-T ; 96..127: Wo-T ; bx==128: rk0 = r@Wr (n range by*32..+32) ; bx>=129: LN row
__global__ __launch_bounds__(256) void prep_k(const float* __restrict__ Wqkv, u16* __restrict__ wqkvT,
                                              const float* __restrict__ Wo, u16* __restrict__ woT,
                                              const float* __restrict__ r, const float* __restrict__ Wr,
                                              float* __restrict__ rk0,
                                              const float* __restrict__ x, const float* __restrict__ gw,
                                              const float* __restrict__ bw, u16* __restrict__ xnb){
  __shared__ float tile[32][33];
  __shared__ float red[8];
  const int tx = threadIdx.x, ty = threadIdx.y;
  const int t = ty * 32 + tx;
  if(blockIdx.x == 128){
    // rk0[n] = sum_d r[d] * Wr[d*1024+n]
    const int n = blockIdx.y * 32 + (t & 31);
    const int chunk = t >> 5;                 // 8 chunks of 128 d
    float acc = 0.f;
    const int d0 = chunk * 128;
    for(int d = d0; d < d0 + 128; ++d)
      acc += r[d] * Wr[(size_t)d * 1024 + n];
    tile[chunk][t & 31] = acc;
    __syncthreads();
    if(chunk == 0){
      float s = 0.f;
      #pragma unroll
      for(int c = 0; c < 8; ++c) s += tile[c][t & 31];
      rk0[n] = s;
    }
    return;
  }
  if(blockIdx.x >= 129){
    const int row = (blockIdx.x - 129) * 32 + blockIdx.y;
    const float* xr = x + (size_t)row * 1024;
    float4 xv = *reinterpret_cast<const float4*>(xr + t * 4);
    float s  = xv.x + xv.y + xv.z + xv.w;
    float s2 = xv.x*xv.x + xv.y*xv.y + xv.z*xv.z + xv.w*xv.w;
    #pragma unroll
    for(int m = 1; m <= 32; m <<= 1){ s += __shfl_xor(s, m, 64); s2 += __shfl_xor(s2, m, 64); }
    const int w = t >> 6, lane = t & 63;
    if(lane == 0){ red[w] = s; red[4 + w] = s2; }
    __syncthreads();
    float S1 = red[0] + red[1] + red[2] + red[3];
    float S2 = red[4] + red[5] + red[6] + red[7];
    float mu = S1 * (1.f/1024.f);
    float var = S2 * (1.f/1024.f) - mu * mu;
    float rstd = rsqrtf(var + 1e-5f);
    float4 gv = *reinterpret_cast<const float4*>(gw + t * 4);
    float4 bv = *reinterpret_cast<const float4*>(bw + t * 4);
    ushort4 o;
    o.x = f2bf((xv.x - mu) * rstd * gv.x + bv.x);
    o.y = f2bf((xv.y - mu) * rstd * gv.y + bv.y);
    o.z = f2bf((xv.z - mu) * rstd * gv.z + bv.z);
    o.w = f2bf((xv.w - mu) * rstd * gv.w + bv.w);
    *reinterpret_cast<ushort4*>(xnb + (size_t)row * 1024 + t * 4) = o;
    return;
  }
  const float* in; u16* out; int C, bxx;
  if(blockIdx.x < 96){ in = Wqkv; out = wqkvT; C = 3072; bxx = blockIdx.x; }
  else               { in = Wo;   out = woT;   C = 1024; bxx = blockIdx.x - 96; }
  const int bx = bxx * 32, by = blockIdx.y * 32;
  #pragma unroll
  for(int i = 0; i < 32; i += 8)
    tile[ty + i][tx] = in[(size_t)(by + ty + i) * C + bx + tx];
  __syncthreads();
  #pragma unroll
  for(int i = 0; i < 32; i += 8)
    out[(size_t)(bx + ty + i) * 1024 + by + tx] = f2bf(tile[tx][ty + i]);
}

// ---------- GEMM1 qkv: BK=64; epilogue: bx<16 -> qk ; bx>=16 -> vT via LDS transpose ----------
__global__ __launch_bounds__(256) void gemm_qkv_k(const u16* __restrict__ A, const u16* __restrict__ BT,
                                                  u16* __restrict__ Cb, u16* __restrict__ vT){
  __shared__ u16 sA[2][128 * 32];
  __shared__ u16 sB[2][128 * 32];
  __shared__ u16 tl[128 * 66];          // v epilogue transpose tile (64 cols + 2 pad)
  const int t = threadIdx.x;
  const int row0 = blockIdx.y * 128, col0 = blockIdx.x * 128;
  const int w = t >> 6, lane = t & 63, g = lane >> 4, lq = lane & 15;
  const int wr = (w >> 1) * 64, wc = (w & 1) * 64;
  const int K = 1024;
  f32x4 zero4 = {0.f, 0.f, 0.f, 0.f};
  f32x4 acc[4][4];
  #pragma unroll
  for(int mi = 0; mi < 4; ++mi)
    #pragma unroll
    for(int ni = 0; ni < 4; ++ni) acc[mi][ni] = zero4;

  for(int kt = 0; kt < K; kt += 64){
    #pragma unroll
    for(int ks = 0; ks < 2; ++ks){
      const int kk = kt + ks * 32;
      gld_lds16(A  + (size_t)(row0 +      (t >> 2)) * K + kk + (t & 3) * 8, &sA[ks][w * 512]);
      gld_lds16(A  + (size_t)(row0 + 64 + (t >> 2)) * K + kk + (t & 3) * 8, &sA[ks][2048 + w * 512]);
      gld_lds16(BT + (size_t)(col0 +      (t >> 2)) * K + kk + (t & 3) * 8, &sB[ks][w * 512]);
      gld_lds16(BT + (size_t)(col0 + 64 + (t >> 2)) * K + kk + (t & 3) * 8, &sB[ks][2048 + w * 512]);
    }
    __syncthreads();
    #pragma unroll
    for(int ks = 0; ks < 2; ++ks){
      bf16x8 af[4];
      #pragma unroll
      for(int mi = 0; mi < 4; ++mi)
        af[mi] = *reinterpret_cast<const bf16x8*>(&sA[ks][(wr + mi * 16 + lq) * 32 + g * 8]);
      #pragma unroll
      for(int ni = 0; ni < 4; ++ni){
        bf16x8 bfr = *reinterpret_cast<const bf16x8*>(&sB[ks][(wc + ni * 16 + lq) * 32 + g * 8]);
        #pragma unroll
        for(int mi = 0; mi < 4; ++mi)
          acc[mi][ni] = __builtin_amdgcn_mfma_f32_16x16x32_bf16(af[mi], bfr, acc[mi][ni], 0, 0, 0);
      }
    }
    __syncthreads();
  }
  if(blockIdx.x < 16){
    #pragma unroll
    for(int mi = 0; mi < 4; ++mi)
      #pragma unroll
      for(int ni = 0; ni < 4; ++ni)
        #pragma unroll
        for(int rg = 0; rg < 4; ++rg){
          const int row = row0 + wr + mi * 16 + g * 4 + rg;
          const int col = col0 + wc + ni * 16 + lq;
          Cb[(size_t)row * 2048 + col] = f2bf(acc[mi][ni][rg]);
        }
  } else {
    // v: write vT[(b*16+h)*64+d][i] via LDS transpose, two 64-col halves (one head each)
    const int cv0 = col0 - 2048;          // multiple of 128 -> heads cv0/64, cv0/64+1
    #pragma unroll
    for(int half = 0; half < 2; ++half){
      if((w & 1) == half){                // this wave's cols live in this half
        #pragma unroll
        for(int mi = 0; mi < 4; ++mi)
          #pragma unroll
          for(int ni = 0; ni < 4; ++ni)
            #pragma unroll
            for(int rg = 0; rg < 4; ++rg)
              tl[(wr + mi * 16 + g * 4 + rg) * 66 + ni * 16 + lq] = f2bf(acc[mi][ni][rg]);
      }
      __syncthreads();
      const int h = (cv0 >> 6) + half;
      const int b2 = w >> 1, dup = w & 1, d = lane;   // wave-uniform (b2,dup), lane = d
      const int R = (b2 * 16 + h) * 64 + d;
      u16 tmp[32];
      #pragma unroll
      for(int e = 0; e < 32; ++e)
        tmp[e] = tl[((dup * 32 + e) * 2 + b2) * 66 + d];
      u16* op = vT + (size_t)R * 2048 + (row0 >> 1) + dup * 32;
      *reinterpret_cast<u16x8*>(op)      = *reinterpret_cast<u16x8*>(&tmp[0]);
      *reinterpret_cast<u16x8*>(op + 8)  = *reinterpret_cast<u16x8*>(&tmp[8]);
      *reinterpret_cast<u16x8*>(op + 16) = *reinterpret_cast<u16x8*>(&tmp[16]);
      *reinterpret_cast<u16x8*>(op + 24) = *reinterpret_cast<u16x8*>(&tmp[24]);
      __syncthreads();
    }
  }
}

// ---------- GEMM2 out: f32 = av @ woT^T + residual ----------
__global__ __launch_bounds__(256) void gemm_out_k(const u16* __restrict__ A, const u16* __restrict__ BT,
                                                  const u16* __restrict__ res, float* __restrict__ Cf){
  __shared__ u16 sA[128 * 32];
  __shared__ u16 sB[64 * 32];
  const int t = threadIdx.x;
  const int row0 = blockIdx.y * 128, col0 = blockIdx.x * 64;
  const int w = t >> 6, lane = t & 63, g = lane >> 4, lq = lane & 15;
  const int wr = (w >> 1) * 64, wc = (w & 1) * 32;
  const int K = 1024, N = 1024;
  f32x4 zero4 = {0.f, 0.f, 0.f, 0.f};
  f32x4 acc[4][2];
  #pragma unroll
  for(int mi = 0; mi < 4; ++mi)
    #pragma unroll
    for(int ni = 0; ni < 2; ++ni) acc[mi][ni] = zero4;

  for(int kt = 0; kt < K; kt += 32){
    gld_lds16(A  + (size_t)(row0 +      (t >> 2)) * K + kt + (t & 3) * 8, &sA[w * 512]);
    gld_lds16(A  + (size_t)(row0 + 64 + (t >> 2)) * K + kt + (t & 3) * 8, &sA[2048 + w * 512]);
    gld_lds16(BT + (size_t)(col0 +      (t >> 2)) * K + kt + (t & 3) * 8, &sB[w * 512]);
    __syncthreads();
    bf16x8 af[4];
    #pragma unroll
    for(int mi = 0; mi < 4; ++mi)
      af[mi] = *reinterpret_cast<const bf16x8*>(&sA[(wr + mi * 16 + lq) * 32 + g * 8]);
    #pragma unroll
    for(int ni = 0; ni < 2; ++ni){
      bf16x8 bfr = *reinterpret_cast<const bf16x8*>(&sB[(wc + ni * 16 + lq) * 32 + g * 8]);
      #pragma unroll
      for(int mi = 0; mi < 4; ++mi)
        acc[mi][ni] = __builtin_amdgcn_mfma_f32_16x16x32_bf16(af[mi], bfr, acc[mi][ni], 0, 0, 0);
    }
    __syncthreads();
  }
  #pragma unroll
  for(int mi = 0; mi < 4; ++mi)
    #pragma unroll
    for(int ni = 0; ni < 2; ++ni)
      #pragma unroll
      for(int rg = 0; rg < 4; ++rg){
        const int row = row0 + wr + mi * 16 + g * 4 + rg;
        const int col = col0 + wc + ni * 16 + lq;
        Cf[(size_t)row * N + col] = acc[mi][ni][rg] + bf2f(res[(size_t)row * N + col]);
      }
}

// ---------- flash attention: 32x32x16, S^T form, shfl-exchange P, inline BD dot ----------
// grid: (S/128, B*H, Z); block 256 = 4 waves; wave w owns 32 q-rows [i0+32w, +32).
// Z==2: key-split across BLOCKS (z=0 -> tiles 0..15, z=1 -> 16..31) -> 1024 independent
// 4-wave blocks -> 4 blocks/CU (LDS 4x37888=151.5KB<=160KB, VGPR 4x112<=512/SIMD).
// Unlike r1/r2's 8-wave lockstep split, blocks have independent barriers -> real TLP.
// Partials (f32 acc, rsum) -> avp/rs; comb_k normalizes. Z==1: original single-block path.
__global__ __launch_bounds__(256) void attn_k(const u16* __restrict__ qk, const u16* __restrict__ vT,
                                              const float* __restrict__ rw, const float* __restrict__ rr,
                                              const float* __restrict__ rk0, u16* __restrict__ av,
                                              float* __restrict__ avp, float* __restrict__ rs){
  constexpr int S = 2048, ST = 74;  // 37-dword row stride: 2-way bank aliasing only (free)
  __shared__ u16 ks[2][64 * ST];
  __shared__ u16 vs[2][64 * ST];
  const int t = threadIdx.x;
  const int i0 = blockIdx.x * 128;
  const int bh = blockIdx.y;
  const int z = blockIdx.z;
  const bool split = (gridDim.z == 2);
  const int n0 = z * 16, nt = split ? 16 : 32;
  const int b = bh >> 4, h = bh & 15;
  const int w = t >> 6, lane = t & 63, m = lane & 31, q5 = lane >> 5;
  const int iw0 = i0 + w * 32;
  const int i_lane = iw0 + m;
  const float SC = 0.125f * 1.4426950408889634f;

  // Q B-frags + inline BD dots: ci = sum_d (q[i]+rr)*rk0, cp = same for row i+1
  bf16x8 qf[4];
  float ciL, cpL;
  {
    const bool hasnext = (i_lane + 1 < S);
    const u16* qp  = qk + (size_t)(i_lane * 2 + b) * 2048 + h * 64;
    const u16* qp2 = qk + (size_t)((hasnext ? i_lane + 1 : i_lane) * 2 + b) * 2048 + h * 64;
    const float* rwp = rw  + h * 64;
    const float* rrp = rr  + h * 64;
    const float* rkp = rk0 + h * 64;
    float cpart = 0.f, cppart = 0.f;
    #pragma unroll
    for(int kt = 0; kt < 4; ++kt){
      const int dbase = kt * 16 + q5 * 8;
      u16x8 qv  = *reinterpret_cast<const u16x8*>(qp  + dbase);
      u16x8 qv2 = *reinterpret_cast<const u16x8*>(qp2 + dbase);
      u16x8 a;
      #pragma unroll
      for(int e = 0; e < 8; ++e){
        const float qe  = bf2f(qv[e]);
        const float rke = rkp[dbase + e];
        const float rre = rrp[dbase + e];
        a[e] = f2bf((qe + rwp[dbase + e]) * SC);
        cpart  += (qe + rre) * rke;
        cppart += (bf2f(qv2[e]) + rre) * rke;
      }
      qf[kt] = *reinterpret_cast<bf16x8*>(&a);
    }
    cpart  += __shfl_xor(cpart, 32, 64);   // partner lane holds the other 32 d
    cppart += __shfl_xor(cppart, 32, 64);
    ciL = cpart * SC;
    cpL = hasnext ? cppart * SC : 0.0f;
  }

  f32x16 acc0, acc1, z16;
  #pragma unroll
  for(int e = 0; e < 16; ++e) z16[e] = 0.f;
  acc0 = z16; acc1 = z16;
  float rsum = 0.f;

  const int jr = t >> 2, c0 = (t & 3) * 16;
  {
    const u16* kp = qk + (size_t)((n0 * 64 + jr) * 2 + b) * 2048 + 1024 + h * 64 + c0;
    *reinterpret_cast<u16x8*>(&ks[0][jr * ST + c0])     = *reinterpret_cast<const u16x8*>(kp);
    *reinterpret_cast<u16x8*>(&ks[0][jr * ST + c0 + 8]) = *reinterpret_cast<const u16x8*>(kp + 8);
    const u16* vp = vT + ((size_t)bh * 64 + jr) * 2048 + n0 * 64 + c0;
    *reinterpret_cast<u16x8*>(&vs[0][jr * ST + c0])     = *reinterpret_cast<const u16x8*>(vp);
    *reinterpret_cast<u16x8*>(&vs[0][jr * ST + c0 + 8]) = *reinterpret_cast<const u16x8*>(vp + 8);
  }
  __syncthreads();

  for(int n = n0; n < n0 + nt; ++n){
    const int p = n & 1;                  // n0 is even for both z -> starts at buffer 0
    u16x8 k0, k1, v0, v1;
    const bool pre = (n + 1 < n0 + nt);
    if(pre){
      const int j0n = (n + 1) * 64;
      const u16* kp = qk + (size_t)((j0n + jr) * 2 + b) * 2048 + 1024 + h * 64 + c0;
      k0 = *reinterpret_cast<const u16x8*>(kp);
      k1 = *reinterpret_cast<const u16x8*>(kp + 8);
      const u16* vp = vT + ((size_t)bh * 64 + jr) * 2048 + j0n + c0;
      v0 = *reinterpret_cast<const u16x8*>(vp);
      v1 = *reinterpret_cast<const u16x8*>(vp + 8);
    }
    const int j0 = n * 64;
    bf16x8 pfrag[4];
    #pragma unroll
    for(int jt = 0; jt < 2; ++jt){
      const int tj0 = j0 + jt * 32;
      f32x16 s = z16;
      #pragma unroll
      for(int kt = 0; kt < 4; ++kt){
        bf16x8 ka = *reinterpret_cast<const bf16x8*>(&ks[p][(jt * 32 + m) * ST + kt * 16 + q5 * 8]);
        s = __builtin_amdgcn_mfma_f32_32x32x16_bf16(ka, qf[kt], s, 0, 0, 0);
      }
      float pv[16];
      if(tj0 + 31 <= iw0){
        #pragma unroll
        for(int r2 = 0; r2 < 16; ++r2) pv[r2] = __builtin_amdgcn_exp2f(s[r2] + ciL);
      } else if(tj0 >= iw0 + 33){
        #pragma unroll
        for(int r2 = 0; r2 < 16; ++r2) pv[r2] = __builtin_amdgcn_exp2f(s[r2] + cpL);
      } else {
        #pragma unroll
        for(int r2 = 0; r2 < 16; ++r2){
          const int j = tj0 + (r2 & 3) + 8 * (r2 >> 2) + 4 * q5;
          const float t1 = (j <= i_lane) ? ciL : cpL;
          const float bdL = (j == i_lane + 1) ? 0.0f : t1;
          pv[r2] = __builtin_amdgcn_exp2f(s[r2] + bdL);
        }
      }
      #pragma unroll
      for(int r2 = 0; r2 < 16; ++r2) rsum += pv[r2];
      unsigned pk[8];
      #pragma unroll
      for(int q = 0; q < 8; ++q)
        pk[q] = __builtin_amdgcn_perm(fbits(pv[2 * q + 1]), fbits(pv[2 * q]), 0x07060302);
      unsigned sAx = (q5 == 0) ? pk[2] : pk[0];
      unsigned sAy = (q5 == 0) ? pk[3] : pk[1];
      unsigned rAx = (unsigned)__shfl_xor((int)sAx, 32, 64);
      unsigned rAy = (unsigned)__shfl_xor((int)sAy, 32, 64);
      unsigned sBx = (q5 == 0) ? pk[6] : pk[4];
      unsigned sBy = (q5 == 0) ? pk[7] : pk[5];
      unsigned rBx = (unsigned)__shfl_xor((int)sBx, 32, 64);
      unsigned rBy = (unsigned)__shfl_xor((int)sBy, 32, 64);
      union { unsigned u[4]; bf16x8 bf; } f0, f1;
      if(q5 == 0){
        f0.u[0] = pk[0]; f0.u[1] = pk[1]; f0.u[2] = rAx; f0.u[3] = rAy;
        f1.u[0] = pk[4]; f1.u[1] = pk[5]; f1.u[2] = rBx; f1.u[3] = rBy;
      } else {
        f0.u[0] = rAx; f0.u[1] = rAy; f0.u[2] = pk[2]; f0.u[3] = pk[3];
        f1.u[0] = rBx; f1.u[1] = rBy; f1.u[2] = pk[6]; f1.u[3] = pk[7];
      }
      pfrag[jt * 2 + 0] = f0.bf;
      pfrag[jt * 2 + 1] = f1.bf;
    }
    #pragma unroll
    for(int kt = 0; kt < 4; ++kt){
      bf16x8 va0 = *reinterpret_cast<const bf16x8*>(&vs[p][(m) * ST + kt * 16 + q5 * 8]);
      acc0 = __builtin_amdgcn_mfma_f32_32x32x16_bf16(va0, pfrag[kt], acc0, 0, 0, 0);
      bf16x8 va1 = *reinterpret_cast<const bf16x8*>(&vs[p][(32 + m) * ST + kt * 16 + q5 * 8]);
      acc1 = __builtin_amdgcn_mfma_f32_32x32x16_bf16(va1, pfrag[kt], acc1, 0, 0, 0);
    }
    __syncthreads();
    if(pre){
      const int q2 = p ^ 1;
      *reinterpret_cast<u16x8*>(&ks[q2][jr * ST + c0])     = k0;
      *reinterpret_cast<u16x8*>(&ks[q2][jr * ST + c0 + 8]) = k1;
      *reinterpret_cast<u16x8*>(&vs[q2][jr * ST + c0])     = v0;
      *reinterpret_cast<u16x8*>(&vs[q2][jr * ST + c0 + 8]) = v1;
    }
    __syncthreads();
  }
  rsum += __shfl_xor(rsum, 32, 64);
  if(split){
    // partial epilogue: unnormalized f32 acc + rsum. avp layout == av linear layout.
    float* op = avp + (size_t)z * 4194304 + ((size_t)(i_lane * 2 + b) * 16 + h) * 64;
    #pragma unroll
    for(int dt = 0; dt < 2; ++dt){
      const f32x16& A = dt ? acc1 : acc0;
      #pragma unroll
      for(int rq = 0; rq < 4; ++rq){
        float4 o;
        o.x = A[rq * 4 + 0]; o.y = A[rq * 4 + 1]; o.z = A[rq * 4 + 2]; o.w = A[rq * 4 + 3];
        const int d0 = dt * 32 + 8 * rq + 4 * q5;
        *reinterpret_cast<float4*>(op + d0) = o;
      }
    }
    if(q5 == 0) rs[(size_t)z * 65536 + (size_t)(i_lane * 2 + b) * 16 + h] = rsum;
  } else {
    const float rinv = 1.0f / rsum;
    u16* op = av + (size_t)(i_lane * 2 + b) * 1024 + h * 64;
    #pragma unroll
    for(int dt = 0; dt < 2; ++dt){
      const f32x16& A = dt ? acc1 : acc0;
      #pragma unroll
      for(int rq = 0; rq < 4; ++rq){
        ushort4 o;
        o.x = f2bf(A[rq * 4 + 0] * rinv);
        o.y = f2bf(A[rq * 4 + 1] * rinv);
        o.z = f2bf(A[rq * 4 + 2] * rinv);
        o.w = f2bf(A[rq * 4 + 3] * rinv);
        const int d0 = dt * 32 + 8 * rq + 4 * q5;
        *reinterpret_cast<ushort4*>(op + d0) = o;
      }
    }
  }
}

// ---------- combine: av = (avp0 + avp1) / (rs0 + rs1), f32 -> bf16 ----------
// 4M elems, 8 per thread (all 8 share one (row,h) since 8 | 64). grid 2048 x 256.
__global__ __launch_bounds__(256) void comb_k(const float* __restrict__ avp, const float* __restrict__ rs,
                                              u16* __restrict__ av){
  const int gid = blockIdx.x * 256 + threadIdx.x;
  const size_t i8 = (size_t)gid * 8;
  const size_t rowh = i8 >> 6;
  const float rinv = 1.0f / (rs[rowh] + rs[65536 + rowh]);
  const float4 a0 = *reinterpret_cast<const float4*>(avp + i8);
  const float4 a1 = *reinterpret_cast<const float4*>(avp + i8 + 4);
  const float4 b0 = *reinterpret_cast<const float4*>(avp + 4194304 + i8);
  const float4 b1 = *reinterpret_cast<const float4*>(avp + 4194304 + i8 + 4);
  ushort4 o0, o1;
  o0.x = f2bf((a0.x + b0.x) * rinv); o0.y = f2bf((a0.y + b0.y) * rinv);
  o0.z = f2bf((a0.z + b0.z) * rinv); o0.w = f2bf((a0.w + b0.w) * rinv);
  o1.x = f2bf((a1.x + b1.x) * rinv); o1.y = f2bf((a1.y + b1.y) * rinv);
  o1.z = f2bf((a1.z + b1.z) * rinv); o1.w = f2bf((a1.w + b1.w) * rinv);
  *reinterpret_cast<ushort4*>(av + i8)     = o0;
  *reinterpret_cast<ushort4*>(av + i8 + 4) = o1;
}

extern "C" void kernel_launch(void* const* d_in, const int* in_sizes, int n_in,
                              void* d_out, int out_size, void* d_ws, size_t ws_size,
                              hipStream_t stream){
  (void)in_sizes; (void)n_in; (void)out_size;
  const float* x    = (const float*)d_in[0];
  const float* r    = (const float*)d_in[1];
  const float* rw   = (const float*)d_in[2];
  const float* rr   = (const float*)d_in[3];
  const float* ln_g = (const float*)d_in[4];
  const float* ln_b = (const float*)d_in[5];
  const float* Wqkv = (const float*)d_in[6];
  const float* Wr   = (const float*)d_in[7];
  const float* Wo   = (const float*)d_in[8];
  char* ws = (char*)d_ws;
  u16*   xnb   = (u16*)(ws + 0);                    //  8 MB bf16 [4096,1024]
  u16*   qk    = (u16*)(ws + 8388608);              // 16 MB bf16 [4096,2048] (q | k)
  u16*   av    = (u16*)(ws + 25165824);             //  8 MB bf16 [4096,1024]
  u16*   woT   = (u16*)(ws + 33554432);             //  2 MB bf16 [1024,1024]
  u16*   wqkvT = (u16*)(ws + 35651584);             //  6 MB bf16 [3072,1024]
  u16*   vT    = (u16*)(ws + 41943040);             //  8 MB bf16 [32,64,2048]
  float* rk0   = (float*)(ws + 50331648);           //  4 KB f32 [1024]
  float* rs    = (float*)(ws + 50335744);           // 512 KB f32 [2,4096,16]
  float* avp   = (float*)(ws + 50860032);           // 32 MB f32 [2,4096,16,64]
  float* out   = (float*)d_out;
  const bool split = ws_size >= (size_t)84414464;   // need avp+rs; else fall back to 1-block path

  prep_k<<<dim3(257, 32), dim3(32, 8), 0, stream>>>(Wqkv, wqkvT, Wo, woT, r, Wr, rk0,
                                                    x, ln_g, ln_b, xnb);
  gemm_qkv_k<<<dim3(24, 32), 256, 0, stream>>>(xnb, wqkvT, qk, vT);
  if(split){
    attn_k<<<dim3(16, 32, 2), 256, 0, stream>>>(qk, vT, rw, rr, rk0, av, avp, rs);
    comb_k<<<dim3(2048), 256, 0, stream>>>(avp, rs, av);
  } else {
    attn_k<<<dim3(16, 32, 1), 256, 0, stream>>>(qk, vT, rw, rr, rk0, av, avp, rs);
  }
  gemm_out_k<<<dim3(16, 32), 256, 0, stream>>>(av, woT, xnb, out);
}

// Round 4
// 223.076 us; speedup vs baseline: 1.4135x; 1.0545x over previous
//
#include <hip/hip_runtime.h>

typedef unsigned short u16;
typedef __attribute__((ext_vector_type(8))) __bf16 bf16x8;
typedef __attribute__((ext_vector_type(8))) u16 u16x8;
typedef __attribute__((ext_vector_type(2))) unsigned u32x2;
typedef __attribute__((ext_vector_type(4))) float f32x4;
typedef __attribute__((ext_vector_type(16))) float f32x16;

__device__ __forceinline__ float bf2f(u16 u){
  union { unsigned int i; float f; } v; v.i = ((unsigned int)u) << 16; return v.f;
}
__device__ __forceinline__ u16 f2bf(float f){
  union { float f; unsigned int u; } v; v.f = f;
  unsigned int u = v.u;
  u += 0x7FFFu + ((u >> 16) & 1u);
  return (u16)(u >> 16);
}
__device__ __forceinline__ unsigned fbits(float f){
  union { float f; unsigned u; } v; v.f = f; return v.u;
}
// async global->LDS, 16B per lane; LDS dest = wave-uniform base + lane*16
__device__ __forceinline__ void gld_lds16(const u16* g, u16* l){
  __builtin_amdgcn_global_load_lds((const __attribute__((address_space(1))) unsigned int*)g,
                                   (__attribute__((address_space(3))) unsigned int*)l, 16, 0, 0);
}

// ---------- prep: weight transposes + LayerNorm + rk0, one dispatch ----------
// grid (257, 32), block (32,8):
//   bx<96: Wqkv-T ; 96..127: Wo-T ; bx==128: rk0 = r@Wr (n range by*32..+32) ; bx>=129: LN row
__global__ __launch_bounds__(256) void prep_k(const float* __restrict__ Wqkv, u16* __restrict__ wqkvT,
                                              const float* __restrict__ Wo, u16* __restrict__ woT,
                                              const float* __restrict__ r, const float* __restrict__ Wr,
                                              float* __restrict__ rk0,
                                              const float* __restrict__ x, const float* __restrict__ gw,
                                              const float* __restrict__ bw, u16* __restrict__ xnb){
  __shared__ float tile[32][33];
  __shared__ float red[8];
  const int tx = threadIdx.x, ty = threadIdx.y;
  const int t = ty * 32 + tx;
  if(blockIdx.x == 128){
    // rk0[n] = sum_d r[d] * Wr[d*1024+n]
    const int n = blockIdx.y * 32 + (t & 31);
    const int chunk = t >> 5;                 // 8 chunks of 128 d
    float acc = 0.f;
    const int d0 = chunk * 128;
    for(int d = d0; d < d0 + 128; ++d)
      acc += r[d] * Wr[(size_t)d * 1024 + n];
    tile[chunk][t & 31] = acc;
    __syncthreads();
    if(chunk == 0){
      float s = 0.f;
      #pragma unroll
      for(int c = 0; c < 8; ++c) s += tile[c][t & 31];
      rk0[n] = s;
    }
    return;
  }
  if(blockIdx.x >= 129){
    const int row = (blockIdx.x - 129) * 32 + blockIdx.y;
    const float* xr = x + (size_t)row * 1024;
    float4 xv = *reinterpret_cast<const float4*>(xr + t * 4);
    float s  = xv.x + xv.y + xv.z + xv.w;
    float s2 = xv.x*xv.x + xv.y*xv.y + xv.z*xv.z + xv.w*xv.w;
    #pragma unroll
    for(int m = 1; m <= 32; m <<= 1){ s += __shfl_xor(s, m, 64); s2 += __shfl_xor(s2, m, 64); }
    const int w = t >> 6, lane = t & 63;
    if(lane == 0){ red[w] = s; red[4 + w] = s2; }
    __syncthreads();
    float S1 = red[0] + red[1] + red[2] + red[3];
    float S2 = red[4] + red[5] + red[6] + red[7];
    float mu = S1 * (1.f/1024.f);
    float var = S2 * (1.f/1024.f) - mu * mu;
    float rstd = rsqrtf(var + 1e-5f);
    float4 gv = *reinterpret_cast<const float4*>(gw + t * 4);
    float4 bv = *reinterpret_cast<const float4*>(bw + t * 4);
    ushort4 o;
    o.x = f2bf((xv.x - mu) * rstd * gv.x + bv.x);
    o.y = f2bf((xv.y - mu) * rstd * gv.y + bv.y);
    o.z = f2bf((xv.z - mu) * rstd * gv.z + bv.z);
    o.w = f2bf((xv.w - mu) * rstd * gv.w + bv.w);
    *reinterpret_cast<ushort4*>(xnb + (size_t)row * 1024 + t * 4) = o;
    return;
  }
  const float* in; u16* out; int C, bxx;
  if(blockIdx.x < 96){ in = Wqkv; out = wqkvT; C = 3072; bxx = blockIdx.x; }
  else               { in = Wo;   out = woT;   C = 1024; bxx = blockIdx.x - 96; }
  const int bx = bxx * 32, by = blockIdx.y * 32;
  #pragma unroll
  for(int i = 0; i < 32; i += 8)
    tile[ty + i][tx] = in[(size_t)(by + ty + i) * C + bx + tx];
  __syncthreads();
  #pragma unroll
  for(int i = 0; i < 32; i += 8)
    out[(size_t)(bx + ty + i) * 1024 + by + tx] = f2bf(tile[tx][ty + i]);
}

// ---------- GEMM1 qkv: BK=64; epilogue: bx<16 -> qk ; bx>=16 -> vT via LDS transpose ----------
__global__ __launch_bounds__(256) void gemm_qkv_k(const u16* __restrict__ A, const u16* __restrict__ BT,
                                                  u16* __restrict__ Cb, u16* __restrict__ vT){
  __shared__ u16 sA[2][128 * 32];
  __shared__ u16 sB[2][128 * 32];
  __shared__ u16 tl[128 * 66];          // v epilogue transpose tile (64 cols + 2 pad)
  const int t = threadIdx.x;
  const int row0 = blockIdx.y * 128, col0 = blockIdx.x * 128;
  const int w = t >> 6, lane = t & 63, g = lane >> 4, lq = lane & 15;
  const int wr = (w >> 1) * 64, wc = (w & 1) * 64;
  const int K = 1024;
  f32x4 zero4 = {0.f, 0.f, 0.f, 0.f};
  f32x4 acc[4][4];
  #pragma unroll
  for(int mi = 0; mi < 4; ++mi)
    #pragma unroll
    for(int ni = 0; ni < 4; ++ni) acc[mi][ni] = zero4;

  for(int kt = 0; kt < K; kt += 64){
    #pragma unroll
    for(int ks = 0; ks < 2; ++ks){
      const int kk = kt + ks * 32;
      gld_lds16(A  + (size_t)(row0 +      (t >> 2)) * K + kk + (t & 3) * 8, &sA[ks][w * 512]);
      gld_lds16(A  + (size_t)(row0 + 64 + (t >> 2)) * K + kk + (t & 3) * 8, &sA[ks][2048 + w * 512]);
      gld_lds16(BT + (size_t)(col0 +      (t >> 2)) * K + kk + (t & 3) * 8, &sB[ks][w * 512]);
      gld_lds16(BT + (size_t)(col0 + 64 + (t >> 2)) * K + kk + (t & 3) * 8, &sB[ks][2048 + w * 512]);
    }
    __syncthreads();
    #pragma unroll
    for(int ks = 0; ks < 2; ++ks){
      bf16x8 af[4];
      #pragma unroll
      for(int mi = 0; mi < 4; ++mi)
        af[mi] = *reinterpret_cast<const bf16x8*>(&sA[ks][(wr + mi * 16 + lq) * 32 + g * 8]);
      #pragma unroll
      for(int ni = 0; ni < 4; ++ni){
        bf16x8 bfr = *reinterpret_cast<const bf16x8*>(&sB[ks][(wc + ni * 16 + lq) * 32 + g * 8]);
        #pragma unroll
        for(int mi = 0; mi < 4; ++mi)
          acc[mi][ni] = __builtin_amdgcn_mfma_f32_16x16x32_bf16(af[mi], bfr, acc[mi][ni], 0, 0, 0);
      }
    }
    __syncthreads();
  }
  if(blockIdx.x < 16){
    #pragma unroll
    for(int mi = 0; mi < 4; ++mi)
      #pragma unroll
      for(int ni = 0; ni < 4; ++ni)
        #pragma unroll
        for(int rg = 0; rg < 4; ++rg){
          const int row = row0 + wr + mi * 16 + g * 4 + rg;
          const int col = col0 + wc + ni * 16 + lq;
          Cb[(size_t)row * 2048 + col] = f2bf(acc[mi][ni][rg]);
        }
  } else {
    // v: write vT[(b*16+h)*64+d][i] via LDS transpose, two 64-col halves (one head each)
    const int cv0 = col0 - 2048;          // multiple of 128 -> heads cv0/64, cv0/64+1
    #pragma unroll
    for(int half = 0; half < 2; ++half){
      if((w & 1) == half){                // this wave's cols live in this half
        #pragma unroll
        for(int mi = 0; mi < 4; ++mi)
          #pragma unroll
          for(int ni = 0; ni < 4; ++ni)
            #pragma unroll
            for(int rg = 0; rg < 4; ++rg)
              tl[(wr + mi * 16 + g * 4 + rg) * 66 + ni * 16 + lq] = f2bf(acc[mi][ni][rg]);
      }
      __syncthreads();
      const int h = (cv0 >> 6) + half;
      const int b2 = w >> 1, dup = w & 1, d = lane;   // wave-uniform (b2,dup), lane = d
      const int R = (b2 * 16 + h) * 64 + d;
      u16 tmp[32];
      #pragma unroll
      for(int e = 0; e < 32; ++e)
        tmp[e] = tl[((dup * 32 + e) * 2 + b2) * 66 + d];
      u16* op = vT + (size_t)R * 2048 + (row0 >> 1) + dup * 32;
      *reinterpret_cast<u16x8*>(op)      = *reinterpret_cast<u16x8*>(&tmp[0]);
      *reinterpret_cast<u16x8*>(op + 8)  = *reinterpret_cast<u16x8*>(&tmp[8]);
      *reinterpret_cast<u16x8*>(op + 16) = *reinterpret_cast<u16x8*>(&tmp[16]);
      *reinterpret_cast<u16x8*>(op + 24) = *reinterpret_cast<u16x8*>(&tmp[24]);
      __syncthreads();
    }
  }
}

// ---------- GEMM2 out: f32 = av @ woT^T + residual ----------
__global__ __launch_bounds__(256) void gemm_out_k(const u16* __restrict__ A, const u16* __restrict__ BT,
                                                  const u16* __restrict__ res, float* __restrict__ Cf){
  __shared__ u16 sA[128 * 32];
  __shared__ u16 sB[64 * 32];
  const int t = threadIdx.x;
  const int row0 = blockIdx.y * 128, col0 = blockIdx.x * 64;
  const int w = t >> 6, lane = t & 63, g = lane >> 4, lq = lane & 15;
  const int wr = (w >> 1) * 64, wc = (w & 1) * 32;
  const int K = 1024, N = 1024;
  f32x4 zero4 = {0.f, 0.f, 0.f, 0.f};
  f32x4 acc[4][2];
  #pragma unroll
  for(int mi = 0; mi < 4; ++mi)
    #pragma unroll
    for(int ni = 0; ni < 2; ++ni) acc[mi][ni] = zero4;

  for(int kt = 0; kt < K; kt += 32){
    gld_lds16(A  + (size_t)(row0 +      (t >> 2)) * K + kt + (t & 3) * 8, &sA[w * 512]);
    gld_lds16(A  + (size_t)(row0 + 64 + (t >> 2)) * K + kt + (t & 3) * 8, &sA[2048 + w * 512]);
    gld_lds16(BT + (size_t)(col0 +      (t >> 2)) * K + kt + (t & 3) * 8, &sB[w * 512]);
    __syncthreads();
    bf16x8 af[4];
    #pragma unroll
    for(int mi = 0; mi < 4; ++mi)
      af[mi] = *reinterpret_cast<const bf16x8*>(&sA[(wr + mi * 16 + lq) * 32 + g * 8]);
    #pragma unroll
    for(int ni = 0; ni < 2; ++ni){
      bf16x8 bfr = *reinterpret_cast<const bf16x8*>(&sB[(wc + ni * 16 + lq) * 32 + g * 8]);
      #pragma unroll
      for(int mi = 0; mi < 4; ++mi)
        acc[mi][ni] = __builtin_amdgcn_mfma_f32_16x16x32_bf16(af[mi], bfr, acc[mi][ni], 0, 0, 0);
    }
    __syncthreads();
  }
  #pragma unroll
  for(int mi = 0; mi < 4; ++mi)
    #pragma unroll
    for(int ni = 0; ni < 2; ++ni)
      #pragma unroll
      for(int rg = 0; rg < 4; ++rg){
        const int row = row0 + wr + mi * 16 + g * 4 + rg;
        const int col = col0 + wc + ni * 16 + lq;
        Cf[(size_t)row * N + col] = acc[mi][ni][rg] + bf2f(res[(size_t)row * N + col]);
      }
}

// ---------- flash attention: 32x32x16, S^T form, permlane-exchange P, inline BD dot ----------
// grid: (S/128, B*H); block 256 = 4 waves; wave w owns 32 q-rows [i0+32w, +32).
// r4 changes vs r0 (occupancy attacks r1-r3 all falsified; per-CU throughput was constant
// across 2 and 4 blocks/CU -> issue-path saturated; so this round REMOVES work):
//  - ONE barrier/iter (reads hit buf p, writes hit p^1 -> single barrier orders both hazards)
//  - permlane32_swap replaces cndmask+shfl_xor exchange (VALU 1-2cy vs DS-pipe bpermute)
//  - rsum via ones-row MFMA (accS): deletes 32 VALU adds/iter + final shfl; matrix pipe
//    was only 19.5% busy
//  - s_setprio(1) around MFMA clusters (m191: attn +4-7%)
__global__ __launch_bounds__(256) void attn_k(const u16* __restrict__ qk, const u16* __restrict__ vT,
                                              const float* __restrict__ rw, const float* __restrict__ rr,
                                              const float* __restrict__ rk0, u16* __restrict__ av){
  constexpr int S = 2048, ST = 74;  // 37-dword row stride: 2-way bank aliasing only (free)
  __shared__ u16 ks[2][64 * ST];
  __shared__ u16 vs[2][64 * ST];
  const int t = threadIdx.x;
  const int i0 = blockIdx.x * 128;
  const int bh = blockIdx.y;
  const int b = bh >> 4, h = bh & 15;
  const int w = t >> 6, lane = t & 63, m = lane & 31, q5 = lane >> 5;
  const int iw0 = i0 + w * 32;
  const int i_lane = iw0 + m;
  const float SC = 0.125f * 1.4426950408889634f;

  // Q B-frags + inline BD dots: ci = sum_d (q[i]+rr)*rk0, cp = same for row i+1
  bf16x8 qf[4];
  float ciL, cpL;
  {
    const bool hasnext = (i_lane + 1 < S);
    const u16* qp  = qk + (size_t)(i_lane * 2 + b) * 2048 + h * 64;
    const u16* qp2 = qk + (size_t)((hasnext ? i_lane + 1 : i_lane) * 2 + b) * 2048 + h * 64;
    const float* rwp = rw  + h * 64;
    const float* rrp = rr  + h * 64;
    const float* rkp = rk0 + h * 64;
    float cpart = 0.f, cppart = 0.f;
    #pragma unroll
    for(int kt = 0; kt < 4; ++kt){
      const int dbase = kt * 16 + q5 * 8;
      u16x8 qv  = *reinterpret_cast<const u16x8*>(qp  + dbase);
      u16x8 qv2 = *reinterpret_cast<const u16x8*>(qp2 + dbase);
      u16x8 a;
      #pragma unroll
      for(int e = 0; e < 8; ++e){
        const float qe  = bf2f(qv[e]);
        const float rke = rkp[dbase + e];
        const float rre = rrp[dbase + e];
        a[e] = f2bf((qe + rwp[dbase + e]) * SC);
        cpart  += (qe + rre) * rke;
        cppart += (bf2f(qv2[e]) + rre) * rke;
      }
      qf[kt] = *reinterpret_cast<bf16x8*>(&a);
    }
    cpart  += __shfl_xor(cpart, 32, 64);   // partner lane holds the other 32 d
    cppart += __shfl_xor(cppart, 32, 64);
    ciL = cpart * SC;
    cpL = hasnext ? cppart * SC : 0.0f;
  }

  // ones A-frag for the rsum MFMA (bf16 1.0 = 0x3F80)
  union { u16 us[8]; bf16x8 bf; } onesu;
  #pragma unroll
  for(int e = 0; e < 8; ++e) onesu.us[e] = 0x3F80;
  const bf16x8 ones = onesu.bf;

  f32x16 acc0, acc1, accS, z16;
  #pragma unroll
  for(int e = 0; e < 16; ++e) z16[e] = 0.f;
  acc0 = z16; acc1 = z16; accS = z16;

  const int jr = t >> 2, c0 = (t & 3) * 16;
  {
    const u16* kp = qk + (size_t)(jr * 2 + b) * 2048 + 1024 + h * 64 + c0;
    *reinterpret_cast<u16x8*>(&ks[0][jr * ST + c0])     = *reinterpret_cast<const u16x8*>(kp);
    *reinterpret_cast<u16x8*>(&ks[0][jr * ST + c0 + 8]) = *reinterpret_cast<const u16x8*>(kp + 8);
    const u16* vp = vT + ((size_t)bh * 64 + jr) * 2048 + c0;
    *reinterpret_cast<u16x8*>(&vs[0][jr * ST + c0])     = *reinterpret_cast<const u16x8*>(vp);
    *reinterpret_cast<u16x8*>(&vs[0][jr * ST + c0 + 8]) = *reinterpret_cast<const u16x8*>(vp + 8);
  }
  __syncthreads();

  for(int n = 0; n < 32; ++n){
    const int p = n & 1;
    u16x8 k0, k1, v0, v1;
    const bool pre = (n + 1 < 32);
    if(pre){
      const int j0n = (n + 1) * 64;
      const u16* kp = qk + (size_t)((j0n + jr) * 2 + b) * 2048 + 1024 + h * 64 + c0;
      k0 = *reinterpret_cast<const u16x8*>(kp);
      k1 = *reinterpret_cast<const u16x8*>(kp + 8);
      const u16* vp = vT + ((size_t)bh * 64 + jr) * 2048 + j0n + c0;
      v0 = *reinterpret_cast<const u16x8*>(vp);
      v1 = *reinterpret_cast<const u16x8*>(vp + 8);
    }
    const int j0 = n * 64;
    bf16x8 pfrag[4];
    #pragma unroll
    for(int jt = 0; jt < 2; ++jt){
      const int tj0 = j0 + jt * 32;
      f32x16 s = z16;
      __builtin_amdgcn_s_setprio(1);
      #pragma unroll
      for(int kt = 0; kt < 4; ++kt){
        bf16x8 ka = *reinterpret_cast<const bf16x8*>(&ks[p][(jt * 32 + m) * ST + kt * 16 + q5 * 8]);
        s = __builtin_amdgcn_mfma_f32_32x32x16_bf16(ka, qf[kt], s, 0, 0, 0);
      }
      __builtin_amdgcn_s_setprio(0);
      float pv[16];
      if(tj0 + 31 <= iw0){
        #pragma unroll
        for(int r2 = 0; r2 < 16; ++r2) pv[r2] = __builtin_amdgcn_exp2f(s[r2] + ciL);
      } else if(tj0 >= iw0 + 33){
        #pragma unroll
        for(int r2 = 0; r2 < 16; ++r2) pv[r2] = __builtin_amdgcn_exp2f(s[r2] + cpL);
      } else {
        #pragma unroll
        for(int r2 = 0; r2 < 16; ++r2){
          const int j = tj0 + (r2 & 3) + 8 * (r2 >> 2) + 4 * q5;
          const float t1 = (j <= i_lane) ? ciL : cpL;
          const float bdL = (j == i_lane + 1) ? 0.0f : t1;
          pv[r2] = __builtin_amdgcn_exp2f(s[r2] + bdL);
        }
      }
      unsigned pk[8];
      #pragma unroll
      for(int q = 0; q < 8; ++q)
        pk[q] = __builtin_amdgcn_perm(fbits(pv[2 * q + 1]), fbits(pv[2 * q]), 0x07060302);
      union { unsigned u[4]; bf16x8 bf; } f0, f1;
#if __has_builtin(__builtin_amdgcn_permlane32_swap)
      // (out_lo, out_hi) = swap(a, b): out_lo = {a.lo | b.lo@hi}, out_hi = {a.hi@lo | b.hi}
      u32x2 r0 = __builtin_amdgcn_permlane32_swap(pk[0], pk[2], false, false);
      u32x2 r1 = __builtin_amdgcn_permlane32_swap(pk[1], pk[3], false, false);
      u32x2 r2 = __builtin_amdgcn_permlane32_swap(pk[4], pk[6], false, false);
      u32x2 r3 = __builtin_amdgcn_permlane32_swap(pk[5], pk[7], false, false);
      f0.u[0] = r0[0]; f0.u[2] = r0[1];
      f0.u[1] = r1[0]; f0.u[3] = r1[1];
      f1.u[0] = r2[0]; f1.u[2] = r2[1];
      f1.u[1] = r3[0]; f1.u[3] = r3[1];
#else
      unsigned sAx = (q5 == 0) ? pk[2] : pk[0];
      unsigned sAy = (q5 == 0) ? pk[3] : pk[1];
      unsigned rAx = (unsigned)__shfl_xor((int)sAx, 32, 64);
      unsigned rAy = (unsigned)__shfl_xor((int)sAy, 32, 64);
      unsigned sBx = (q5 == 0) ? pk[6] : pk[4];
      unsigned sBy = (q5 == 0) ? pk[7] : pk[5];
      unsigned rBx = (unsigned)__shfl_xor((int)sBx, 32, 64);
      unsigned rBy = (unsigned)__shfl_xor((int)sBy, 32, 64);
      if(q5 == 0){
        f0.u[0] = pk[0]; f0.u[1] = pk[1]; f0.u[2] = rAx; f0.u[3] = rAy;
        f1.u[0] = pk[4]; f1.u[1] = pk[5]; f1.u[2] = rBx; f1.u[3] = rBy;
      } else {
        f0.u[0] = rAx; f0.u[1] = rAy; f0.u[2] = pk[2]; f0.u[3] = pk[3];
        f1.u[0] = rBx; f1.u[1] = rBy; f1.u[2] = pk[6]; f1.u[3] = pk[7];
      }
#endif
      pfrag[jt * 2 + 0] = f0.bf;
      pfrag[jt * 2 + 1] = f1.bf;
    }
    __builtin_amdgcn_s_setprio(1);
    #pragma unroll
    for(int kt = 0; kt < 4; ++kt){
      bf16x8 va0 = *reinterpret_cast<const bf16x8*>(&vs[p][(m) * ST + kt * 16 + q5 * 8]);
      acc0 = __builtin_amdgcn_mfma_f32_32x32x16_bf16(va0, pfrag[kt], acc0, 0, 0, 0);
      bf16x8 va1 = *reinterpret_cast<const bf16x8*>(&vs[p][(32 + m) * ST + kt * 16 + q5 * 8]);
      acc1 = __builtin_amdgcn_mfma_f32_32x32x16_bf16(va1, pfrag[kt], acc1, 0, 0, 0);
      accS = __builtin_amdgcn_mfma_f32_32x32x16_bf16(ones, pfrag[kt], accS, 0, 0, 0);
    }
    __builtin_amdgcn_s_setprio(0);
    // single barrier per iter: this iter reads buf p and writes buf p^1 (disjoint), so one
    // barrier orders writes(p^1)@n before reads(p^1)@n+1 AND reads(p)@n before writes(p)@n+1.
    if(pre){
      const int q2 = p ^ 1;
      *reinterpret_cast<u16x8*>(&ks[q2][jr * ST + c0])     = k0;
      *reinterpret_cast<u16x8*>(&ks[q2][jr * ST + c0 + 8]) = k1;
      *reinterpret_cast<u16x8*>(&vs[q2][jr * ST + c0])     = v0;
      *reinterpret_cast<u16x8*>(&vs[q2][jr * ST + c0 + 8]) = v1;
    }
    __syncthreads();
  }
  // accS: every reg = sum_j P[j, q=m] (ones-row matmul) -> softmax denominator, no shuffle
  const float rinv = 1.0f / accS[0];
  u16* op = av + (size_t)(i_lane * 2 + b) * 1024 + h * 64;
  #pragma unroll
  for(int dt = 0; dt < 2; ++dt){
    const f32x16& A = dt ? acc1 : acc0;
    #pragma unroll
    for(int rq = 0; rq < 4; ++rq){
      ushort4 o;
      o.x = f2bf(A[rq * 4 + 0] * rinv);
      o.y = f2bf(A[rq * 4 + 1] * rinv);
      o.z = f2bf(A[rq * 4 + 2] * rinv);
      o.w = f2bf(A[rq * 4 + 3] * rinv);
      const int d0 = dt * 32 + 8 * rq + 4 * q5;
      *reinterpret_cast<ushort4*>(op + d0) = o;
    }
  }
}

extern "C" void kernel_launch(void* const* d_in, const int* in_sizes, int n_in,
                              void* d_out, int out_size, void* d_ws, size_t ws_size,
                              hipStream_t stream){
  (void)in_sizes; (void)n_in; (void)out_size; (void)ws_size;
  const float* x    = (const float*)d_in[0];
  const float* r    = (const float*)d_in[1];
  const float* rw   = (const float*)d_in[2];
  const float* rr   = (const float*)d_in[3];
  const float* ln_g = (const float*)d_in[4];
  const float* ln_b = (const float*)d_in[5];
  const float* Wqkv = (const float*)d_in[6];
  const float* Wr   = (const float*)d_in[7];
  const float* Wo   = (const float*)d_in[8];
  char* ws = (char*)d_ws;
  u16*   xnb   = (u16*)(ws + 0);                    //  8 MB bf16 [4096,1024]
  u16*   qk    = (u16*)(ws + 8388608);              // 16 MB bf16 [4096,2048] (q | k)
  u16*   av    = (u16*)(ws + 25165824);             //  8 MB bf16 [4096,1024]
  u16*   woT   = (u16*)(ws + 33554432);             //  2 MB bf16 [1024,1024]
  u16*   wqkvT = (u16*)(ws + 35651584);             //  6 MB bf16 [3072,1024]
  u16*   vT    = (u16*)(ws + 41943040);             //  8 MB bf16 [32,64,2048]
  float* rk0   = (float*)(ws + 50331648);           //  4 KB f32 [1024]
  float* out   = (float*)d_out;

  prep_k<<<dim3(257, 32), dim3(32, 8), 0, stream>>>(Wqkv, wqkvT, Wo, woT, r, Wr, rk0,
                                                    x, ln_g, ln_b, xnb);
  gemm_qkv_k<<<dim3(24, 32), 256, 0, stream>>>(xnb, wqkvT, qk, vT);
  attn_k<<<dim3(16, 32), 256, 0, stream>>>(qk, vT, rw, rr, rk0, av);
  gemm_out_k<<<dim3(16, 32), 256, 0, stream>>>(av, woT, xnb, out);
}